// Round 11
// baseline (121.671 us; speedup 1.0000x reference)
//
#include <hip/hip_runtime.h>
#include <math.h>

// Match x86 reference LAPACK (no FMA contraction anywhere in the emulation).
#pragma clang fp contract(off)

#define NIT 35      // provable: prob=min(...,0.99)<=0.99 => k<=35.49 => reason<=35 => no update past it=34
#define BB  32
#define NPTS 32768
#define MGRP 7      // models per count-block
#define NGRP 5      // NIT = MGRP * NGRP
#define CBLOCKS (NGRP*8*BB)   // 1280 count blocks

// ---------------- LAPACK helpers (fp32, faithful) ----------------

__device__ __forceinline__ float slapy2f(float x, float y){
  float xa = fabsf(x), ya = fabsf(y);
  float w = fmaxf(xa, ya), z = fminf(xa, ya);
  if (z == 0.0f) return w;
  float q = z / w;
  return w * sqrtf(1.0f + q*q);
}

// LAPACK >= 3.10 slartg (modern OpenBLAS as shipped with numpy/scipy).
__device__ __forceinline__ void slartgf(float f, float g, float* cs, float* sn, float* r){
  if (g == 0.0f){ *cs = 1.0f; *sn = 0.0f; *r = f; return; }
  if (f == 0.0f){ *cs = 0.0f; *sn = copysignf(1.0f, g); *r = fabsf(g); return; }
  float f1 = fabsf(f);
  float d  = sqrtf(f*f + g*g);
  *cs = f1 / d;
  *r  = copysignf(d, f);
  *sn = g / (*r);
}

__device__ void slaev2f(float a, float b, float c,
                        float* rt1, float* rt2, float* cs1, float* sn1){
  float sm  = a + c;
  float df  = a - c;
  float adf = fabsf(df);
  float tb  = b + b;
  float ab  = fabsf(tb);
  float acmx, acmn;
  if (fabsf(a) > fabsf(c)){ acmx = a; acmn = c; } else { acmx = c; acmn = a; }
  float rt;
  if (adf > ab){ float q = ab/adf; rt = adf*sqrtf(1.0f + q*q); }
  else if (adf < ab){ float q = adf/ab; rt = ab*sqrtf(1.0f + q*q); }
  else rt = ab*sqrtf(2.0f);
  int sgn1;
  if (sm < 0.0f){
    *rt1 = 0.5f*(sm - rt); sgn1 = -1;
    *rt2 = (acmx / *rt1)*acmn - (b / *rt1)*b;
  } else if (sm > 0.0f){
    *rt1 = 0.5f*(sm + rt); sgn1 = 1;
    *rt2 = (acmx / *rt1)*acmn - (b / *rt1)*b;
  } else {
    *rt1 = 0.5f*rt; *rt2 = -0.5f*rt; sgn1 = 1;
  }
  float cs; int sgn2;
  if (df >= 0.0f){ cs = df + rt; sgn2 = 1; } else { cs = df - rt; sgn2 = -1; }
  float acs = fabsf(cs);
  float cs1v, sn1v;
  if (acs > ab){
    float ct = -tb/cs;
    sn1v = 1.0f/sqrtf(1.0f + ct*ct);
    cs1v = ct*sn1v;
  } else {
    if (ab == 0.0f){ cs1v = 1.0f; sn1v = 0.0f; }
    else {
      float tn = -cs/tb;
      cs1v = 1.0f/sqrtf(1.0f + tn*tn);
      sn1v = tn*cs1v;
    }
  }
  if (sgn1 == sgn2){ float t = cs1v; cs1v = -sn1v; sn1v = t; }
  *cs1 = cs1v; *sn1 = sn1v;
}

// ---- register-resident dynamic access (R2-proven text) — cold paths only ----
#define RD_D(i)   ((i)==1?d1:(i)==2?d2:(i)==3?d3:d4)
#define WR_D(i,v) do{ float _v=(v); int _ix=(i); if(_ix==1)d1=_v; else if(_ix==2)d2=_v; else if(_ix==3)d3=_v; else d4=_v; }while(0)
#define RD_E(i)   ((i)==1?e1:(i)==2?e2:(i)==3?e3:e4)
#define WR_E(i,v) do{ float _v=(v); int _ix=(i); if(_ix==1)e1=_v; else if(_ix==2)e2=_v; else if(_ix==3)e3=_v; else e4=_v; }while(0)
#define RD_W(i)   ((i)==1?w1:(i)==2?w2:(i)==3?w3:(i)==4?w4:(i)==5?w5:(i)==6?w6:w7)
#define WR_W(i,v) do{ float _v=(v); int _ix=(i); if(_ix==1)w1=_v; else if(_ix==2)w2=_v; else if(_ix==3)w3=_v; else if(_ix==4)w4=_v; else if(_ix==5)w5=_v; else if(_ix==6)w6=_v; else w7=_v; }while(0)
#define RD_Z(i,j) ((j)==1? z##i##1 : (j)==2? z##i##2 : (j)==3? z##i##3 : z##i##4)
#define WR_Z(i,j,v) do{ float _vv=(v); int _jj=(j); \
  if(_jj==1) z##i##1=_vv; else if(_jj==2) z##i##2=_vv; else if(_jj==3) z##i##3=_vv; else z##i##4=_vv; }while(0)
#define ROTZ_ROW(i,jv,cv,sv) do{ \
  float _t = RD_Z(i,(jv)); float _o = RD_Z(i,(jv)-1); \
  float _nt = (cv)*_t - (sv)*_o; \
  float _no = (sv)*_t + (cv)*_o; \
  WR_Z(i,(jv),_nt); WR_Z(i,(jv)-1,_no); \
}while(0)
#define ROTZ(jv,cv,sv) do{ int _rj=(jv); float _rc=(cv), _rs=(sv); \
  ROTZ_ROW(1,_rj,_rc,_rs); ROTZ_ROW(2,_rj,_rc,_rs); ROTZ_ROW(3,_rj,_rc,_rs); ROTZ_ROW(4,_rj,_rc,_rs); }while(0)

// ---------------- Kernel 1: one (it,b) problem per WAVE (verbatim R10-proven) ----------------

__global__ void __launch_bounds__(64) models_kernel(const float* __restrict__ data,
                                                    const int* __restrict__ idx,
                                                    float* __restrict__ models,
                                                    int* __restrict__ counts,
                                                    int* __restrict__ done){
  const int t = blockIdx.x;              // 0..NIT*BB-1; all 64 lanes compute redundantly
  if (threadIdx.x == 0){
    counts[t] = 0;                       // count dispatch is later; stream order safe
    if (t == 0) *done = 0;               // arrival counter for fused count+scan
  }
  const int it = t >> 5;
  const int b  = t & 31;

  // gather 3 samples, aug rows [x,y,z,1]
  float P[3][4];
  const int* ip = &idx[(it*BB + b)*3];
  #pragma unroll
  for (int s=0;s<3;s++){
    int n = ip[s];
    const float* pp = &data[((long)b*NPTS + n)*3];
    P[s][0]=pp[0]; P[s][1]=pp[1]; P[s][2]=pp[2]; P[s][3]=1.0f;
  }
  // A = aug^T aug (sum over s in order 0,1,2; separate rounding)
  float A[5][5];
  #pragma unroll
  for (int i=0;i<4;i++)
    #pragma unroll
    for (int j=0;j<4;j++){
      float acc = P[0][i]*P[0][j];
      acc = acc + P[1][i]*P[1][j];
      acc = acc + P[2][i]*P[2][j];
      A[i+1][j+1] = acc;
    }

  // ssytd2 (UPLO='L', n=4): reference-BLAS op ordering
  float eE[5], tauv[4];
  #pragma unroll
  for (int i=1;i<=3;i++){
    float alpha = A[i+1][i];
    float ssq = 0.0f;
    #pragma unroll
    for (int k=i+2;k<=4;k++) ssq = ssq + A[k][i]*A[k][i];
    float xnorm = sqrtf(ssq);
    float taui;
    if (xnorm == 0.0f){
      taui = 0.0f;
    } else {
      float beta = -copysignf(slapy2f(alpha, xnorm), alpha);
      taui = (beta - alpha)/beta;
      float sc = 1.0f/(alpha - beta);
      #pragma unroll
      for (int k=i+2;k<=4;k++) A[k][i] = A[k][i]*sc;
      alpha = beta;
    }
    eE[i] = alpha;
    if (taui != 0.0f){
      A[i+1][i] = 1.0f;
      float w[5];
      #pragma unroll
      for (int r=i+1;r<=4;r++) w[r] = 0.0f;
      // ssymv('L'): w = taui * Asub * v
      #pragma unroll
      for (int j=i+1;j<=4;j++){
        float temp1 = taui*A[j][i];
        float temp2 = 0.0f;
        w[j] = w[j] + temp1*A[j][j];
        #pragma unroll
        for (int r=j+1;r<=4;r++){
          w[r] = w[r] + temp1*A[r][j];
          temp2 = temp2 + A[r][j]*A[r][i];
        }
        w[j] = w[j] + taui*temp2;
      }
      float dot = 0.0f;
      #pragma unroll
      for (int r=i+1;r<=4;r++) dot = dot + w[r]*A[r][i];
      float alpha2 = (-0.5f*taui)*dot;
      #pragma unroll
      for (int r=i+1;r<=4;r++) w[r] = w[r] + alpha2*A[r][i];
      // ssyr2('L', alpha=-1)
      #pragma unroll
      for (int j=i+1;j<=4;j++){
        float xj = A[j][i], yj = w[j];
        if (xj != 0.0f || yj != 0.0f){
          float temp1 = -yj;
          float temp2 = -xj;
          #pragma unroll
          for (int r=j;r<=4;r++){
            float acc = A[r][j] + A[r][i]*temp1;
            acc = acc + w[r]*temp2;
            A[r][j] = acc;
          }
        }
      }
    }
    tauv[i] = taui;
  }

  // ---------------- ssteqr('I', n=4), all state in registers ----------------
  float d1=A[1][1], d2=A[2][2], d3=A[3][3], d4=A[4][4];
  float e1=eE[1], e2=eE[2], e3=eE[3], e4=0.0f;
  float w1=0,w2=0,w3=0,w4=0,w5=0,w6=0,w7=0;
  float z11=1,z12=0,z13=0,z14=0;
  float z21=0,z22=1,z23=0,z24=0;
  float z31=0,z32=0,z33=1,z34=0;
  float z41=0,z42=0,z43=0,z44=1;
  (void)e4; (void)w7;

  {
    const float eps    = 5.9604645e-08f;
    const float eps2   = eps*eps;
    const float safmin = 1.17549435e-38f;
    const int nmaxit = 4*30;
    int jtot = 0;

    int l1 = 1;
    while (l1 <= 4){
      if (l1 > 1) WR_E(l1-1, 0.0f);
      // ---- outer m-scan, statically unrolled on l1 (R8-proven) ----
      int m = 4;
      do {
        if (l1 == 1){
          float tst = fabsf(e1);
          if (tst == 0.0f){ m = 1; break; }
          if (tst <= (sqrtf(fabsf(d1)) * sqrtf(fabsf(d2))) * eps){ e1 = 0.0f; m = 1; break; }
        }
        if (l1 <= 2){
          float tst = fabsf(e2);
          if (tst == 0.0f){ m = 2; break; }
          if (tst <= (sqrtf(fabsf(d2)) * sqrtf(fabsf(d3))) * eps){ e2 = 0.0f; m = 2; break; }
        }
        if (l1 <= 3){
          float tst = fabsf(e3);
          if (tst == 0.0f){ m = 3; break; }
          if (tst <= (sqrtf(fabsf(d3)) * sqrtf(fabsf(d4))) * eps){ e3 = 0.0f; m = 3; break; }
        }
      } while(0);
      int l = l1, lsv = l, lend = m, lendsv = lend;
      l1 = m + 1;
      if (lend == l) continue;

      // ---- anorm + direction swap, statically specialized (R10-proven) ----
      {
        float anorm; bool sw;
        if (l == 1){
          if (lend == 2){
            anorm = fmaxf(fmaxf(0.0f, fabsf(d1)), fabsf(d2));
            anorm = fmaxf(anorm, fabsf(e1));
            sw = fabsf(d2) < fabsf(d1);
          } else if (lend == 3){
            anorm = fmaxf(fmaxf(fmaxf(0.0f, fabsf(d1)), fabsf(d2)), fabsf(d3));
            anorm = fmaxf(fmaxf(anorm, fabsf(e1)), fabsf(e2));
            sw = fabsf(d3) < fabsf(d1);
          } else {
            anorm = fmaxf(fmaxf(fmaxf(fmaxf(0.0f, fabsf(d1)), fabsf(d2)), fabsf(d3)), fabsf(d4));
            anorm = fmaxf(fmaxf(fmaxf(anorm, fabsf(e1)), fabsf(e2)), fabsf(e3));
            sw = fabsf(d4) < fabsf(d1);
          }
        } else if (l == 2){
          if (lend == 3){
            anorm = fmaxf(fmaxf(0.0f, fabsf(d2)), fabsf(d3));
            anorm = fmaxf(anorm, fabsf(e2));
            sw = fabsf(d3) < fabsf(d2);
          } else {
            anorm = fmaxf(fmaxf(fmaxf(0.0f, fabsf(d2)), fabsf(d3)), fabsf(d4));
            anorm = fmaxf(fmaxf(anorm, fabsf(e2)), fabsf(e3));
            sw = fabsf(d4) < fabsf(d2);
          }
        } else { // l==3, lend==4
          anorm = fmaxf(fmaxf(0.0f, fabsf(d3)), fabsf(d4));
          anorm = fmaxf(anorm, fabsf(e3));
          sw = fabsf(d4) < fabsf(d3);
        }
        if (anorm == 0.0f) continue;
        if (sw){ lend = lsv; l = lendsv; }
      }

      if (lend > l){
        // ---------------- QL iteration ----------------
        for(;;){
          // ---- inner deflation scan, statically unrolled (R8-proven) ----
          int m2 = lend;
          if (l != lend){
            do {
              if (l <= 1){                    // mm=1 (lend>=2 since lend>l)
                float tst = e1*e1;
                if (tst <= (eps2*fabsf(d1))*fabsf(d2) + safmin){ m2 = 1; break; }
              }
              if (l <= 2 && lend >= 3){       // mm=2
                float tst = e2*e2;
                if (tst <= (eps2*fabsf(d2))*fabsf(d3) + safmin){ m2 = 2; break; }
              }
              if (l <= 3 && lend >= 4){       // mm=3
                float tst = e3*e3;
                if (tst <= (eps2*fabsf(d3))*fabsf(d4) + safmin){ m2 = 3; break; }
              }
            } while(0);
          }
          if (m2 < lend) WR_E(m2, 0.0f);
          float p = RD_D(l);
          if (m2 == l){
            WR_D(l, p); l = l + 1;
            if (l <= lend) continue;
            break;
          }
          if (m2 == l+1){
            float rt1, rt2, c1, s1;
            if (l == 1){
              slaev2f(d1, e1, d2, &rt1, &rt2, &c1, &s1);
              w1 = c1; w4 = s1;
              ROTZ(2, c1, s1);
              d1 = rt1; d2 = rt2; e1 = 0.0f;
            } else if (l == 2){
              slaev2f(d2, e2, d3, &rt1, &rt2, &c1, &s1);
              w2 = c1; w5 = s1;
              ROTZ(3, c1, s1);
              d2 = rt1; d3 = rt2; e2 = 0.0f;
            } else {
              slaev2f(d3, e3, d4, &rt1, &rt2, &c1, &s1);
              w3 = c1; w6 = s1;
              ROTZ(4, c1, s1);
              d3 = rt1; d4 = rt2; e3 = 0.0f;
            }
            l = l + 2;
            if (l <= lend) continue;
            break;
          }
          if (jtot == nmaxit) break;
          jtot++;
          {
            float g, r, s = 1.0f, c = 1.0f;
            if (l == 1 && m2 == 3){
              g = (d2 - p) / (2.0f*e1);
              r = slapy2f(g, 1.0f);
              g = d3 - p + (e1 / (g + copysignf(r, g)));
              p = 0.0f;
              { // i=2 (first: no e-write)
                float f = s*e2, bq = c*e2;
                slartgf(g, f, &c, &s, &r);
                g = d3 - p;
                r = (d2 - g)*s + (2.0f*c)*bq;
                p = s*r;
                d3 = g + p;
                g = c*r - bq;
                w2 = c; w5 = -s;
              }
              { // i=1
                float f = s*e1, bq = c*e1;
                slartgf(g, f, &c, &s, &r);
                e2 = r;
                g = d2 - p;
                r = (d1 - g)*s + (2.0f*c)*bq;
                p = s*r;
                d2 = g + p;
                g = c*r - bq;
                w1 = c; w4 = -s;
              }
              if (w2 != 1.0f || w5 != 0.0f) ROTZ(3, w2, w5);
              if (w1 != 1.0f || w4 != 0.0f) ROTZ(2, w1, w4);
              d1 = d1 - p;
              e1 = g;
            } else if (l == 1 && m2 == 4){
              g = (d2 - p) / (2.0f*e1);
              r = slapy2f(g, 1.0f);
              g = d4 - p + (e1 / (g + copysignf(r, g)));
              p = 0.0f;
              { // i=3 (first)
                float f = s*e3, bq = c*e3;
                slartgf(g, f, &c, &s, &r);
                g = d4 - p;
                r = (d3 - g)*s + (2.0f*c)*bq;
                p = s*r;
                d4 = g + p;
                g = c*r - bq;
                w3 = c; w6 = -s;
              }
              { // i=2
                float f = s*e2, bq = c*e2;
                slartgf(g, f, &c, &s, &r);
                e3 = r;
                g = d3 - p;
                r = (d2 - g)*s + (2.0f*c)*bq;
                p = s*r;
                d3 = g + p;
                g = c*r - bq;
                w2 = c; w5 = -s;
              }
              { // i=1
                float f = s*e1, bq = c*e1;
                slartgf(g, f, &c, &s, &r);
                e2 = r;
                g = d2 - p;
                r = (d1 - g)*s + (2.0f*c)*bq;
                p = s*r;
                d2 = g + p;
                g = c*r - bq;
                w1 = c; w4 = -s;
              }
              if (w3 != 1.0f || w6 != 0.0f) ROTZ(4, w3, w6);
              if (w2 != 1.0f || w5 != 0.0f) ROTZ(3, w2, w5);
              if (w1 != 1.0f || w4 != 0.0f) ROTZ(2, w1, w4);
              d1 = d1 - p;
              e1 = g;
            } else if (l == 2 && m2 == 4){
              g = (d3 - p) / (2.0f*e2);
              r = slapy2f(g, 1.0f);
              g = d4 - p + (e2 / (g + copysignf(r, g)));
              p = 0.0f;
              { // i=3 (first)
                float f = s*e3, bq = c*e3;
                slartgf(g, f, &c, &s, &r);
                g = d4 - p;
                r = (d3 - g)*s + (2.0f*c)*bq;
                p = s*r;
                d4 = g + p;
                g = c*r - bq;
                w3 = c; w6 = -s;
              }
              { // i=2
                float f = s*e2, bq = c*e2;
                slartgf(g, f, &c, &s, &r);
                e3 = r;
                g = d3 - p;
                r = (d2 - g)*s + (2.0f*c)*bq;
                p = s*r;
                d3 = g + p;
                g = c*r - bq;
                w2 = c; w5 = -s;
              }
              if (w3 != 1.0f || w6 != 0.0f) ROTZ(4, w3, w6);
              if (w2 != 1.0f || w5 != 0.0f) ROTZ(3, w2, w5);
              d2 = d2 - p;
              e2 = g;
            } else {
              // defensive fallback: original dynamic text
              g = (RD_D(l+1) - p) / (2.0f*RD_E(l));
              r = slapy2f(g, 1.0f);
              g = RD_D(m2) - p + (RD_E(l) / (g + copysignf(r, g)));
              s = 1.0f; c = 1.0f;
              p = 0.0f;
              for (int i = m2-1; i >= l; i--){
                float f  = s*RD_E(i);
                float bq = c*RD_E(i);
                slartgf(g, f, &c, &s, &r);
                if (i != m2-1) WR_E(i+1, r);
                g = RD_D(i+1) - p;
                r = (RD_D(i) - g)*s + (2.0f*c)*bq;
                p = s*r;
                WR_D(i+1, g + p);
                g = c*r - bq;
                WR_W(i, c);
                WR_W(3+i, -s);
              }
              int mmn = m2 - l + 1;    // slasr('R','V','B')
              for (int j = mmn-1; j >= 1; j--){
                float ct = RD_W(l+j-1), sx = RD_W(3+l+j-1);
                if (ct != 1.0f || sx != 0.0f) ROTZ(l+j, ct, sx);
              }
              WR_D(l, RD_D(l) - p);
              WR_E(l, g);
            }
          }
        }
      } else {
        // ---------------- QR iteration ----------------
        for(;;){
          // ---- inner deflation scan, statically unrolled (R8-proven) ----
          int m2 = lend;
          if (l != lend){
            do {
              if (l >= 4){                    // mm=4 (lend<=3 since lend<l)
                float tst = e3*e3;
                if (tst <= (eps2*fabsf(d4))*fabsf(d3) + safmin){ m2 = 4; break; }
              }
              if (l >= 3 && lend <= 2){       // mm=3
                float tst = e2*e2;
                if (tst <= (eps2*fabsf(d3))*fabsf(d2) + safmin){ m2 = 3; break; }
              }
              if (l >= 2 && lend <= 1){       // mm=2
                float tst = e1*e1;
                if (tst <= (eps2*fabsf(d2))*fabsf(d1) + safmin){ m2 = 2; break; }
              }
            } while(0);
          }
          if (m2 > lend) WR_E(m2-1, 0.0f);
          float p = RD_D(l);
          if (m2 == l){
            WR_D(l, p); l = l - 1;
            if (l >= lend) continue;
            break;
          }
          if (m2 == l-1){
            float rt1, rt2, c1, s1;
            if (l == 2){
              slaev2f(d1, e1, d2, &rt1, &rt2, &c1, &s1);
              w1 = c1; w4 = s1;
              ROTZ(2, c1, s1);
              d1 = rt1; d2 = rt2; e1 = 0.0f;
            } else if (l == 3){
              slaev2f(d2, e2, d3, &rt1, &rt2, &c1, &s1);
              w2 = c1; w5 = s1;
              ROTZ(3, c1, s1);
              d2 = rt1; d3 = rt2; e2 = 0.0f;
            } else {
              slaev2f(d3, e3, d4, &rt1, &rt2, &c1, &s1);
              w3 = c1; w6 = s1;
              ROTZ(4, c1, s1);
              d3 = rt1; d4 = rt2; e3 = 0.0f;
            }
            l = l - 2;
            if (l >= lend) continue;
            break;
          }
          if (jtot == nmaxit) break;
          jtot++;
          {
            float g, r, s = 1.0f, c = 1.0f;
            if (l == 3 && m2 == 1){
              g = (d2 - p) / (2.0f*e2);
              r = slapy2f(g, 1.0f);
              g = d1 - p + (e2 / (g + copysignf(r, g)));
              p = 0.0f;
              { // i=1 (first: no e-write)
                float f = s*e1, bq = c*e1;
                slartgf(g, f, &c, &s, &r);
                g = d1 - p;
                r = (d2 - g)*s + (2.0f*c)*bq;
                p = s*r;
                d1 = g + p;
                g = c*r - bq;
                w1 = c; w4 = s;
              }
              { // i=2
                float f = s*e2, bq = c*e2;
                slartgf(g, f, &c, &s, &r);
                e1 = r;
                g = d2 - p;
                r = (d3 - g)*s + (2.0f*c)*bq;
                p = s*r;
                d2 = g + p;
                g = c*r - bq;
                w2 = c; w5 = s;
              }
              if (w1 != 1.0f || w4 != 0.0f) ROTZ(2, w1, w4);
              if (w2 != 1.0f || w5 != 0.0f) ROTZ(3, w2, w5);
              d3 = d3 - p;
              e2 = g;
            } else if (l == 4 && m2 == 1){
              g = (d3 - p) / (2.0f*e3);
              r = slapy2f(g, 1.0f);
              g = d1 - p + (e3 / (g + copysignf(r, g)));
              p = 0.0f;
              { // i=1 (first)
                float f = s*e1, bq = c*e1;
                slartgf(g, f, &c, &s, &r);
                g = d1 - p;
                r = (d2 - g)*s + (2.0f*c)*bq;
                p = s*r;
                d1 = g + p;
                g = c*r - bq;
                w1 = c; w4 = s;
              }
              { // i=2
                float f = s*e2, bq = c*e2;
                slartgf(g, f, &c, &s, &r);
                e1 = r;
                g = d2 - p;
                r = (d3 - g)*s + (2.0f*c)*bq;
                p = s*r;
                d2 = g + p;
                g = c*r - bq;
                w2 = c; w5 = s;
              }
              { // i=3
                float f = s*e3, bq = c*e3;
                slartgf(g, f, &c, &s, &r);
                e2 = r;
                g = d3 - p;
                r = (d4 - g)*s + (2.0f*c)*bq;
                p = s*r;
                d3 = g + p;
                g = c*r - bq;
                w3 = c; w6 = s;
              }
              if (w1 != 1.0f || w4 != 0.0f) ROTZ(2, w1, w4);
              if (w2 != 1.0f || w5 != 0.0f) ROTZ(3, w2, w5);
              if (w3 != 1.0f || w6 != 0.0f) ROTZ(4, w3, w6);
              d4 = d4 - p;
              e3 = g;
            } else if (l == 4 && m2 == 2){
              g = (d3 - p) / (2.0f*e3);
              r = slapy2f(g, 1.0f);
              g = d2 - p + (e3 / (g + copysignf(r, g)));
              p = 0.0f;
              { // i=2 (first)
                float f = s*e2, bq = c*e2;
                slartgf(g, f, &c, &s, &r);
                g = d2 - p;
                r = (d3 - g)*s + (2.0f*c)*bq;
                p = s*r;
                d2 = g + p;
                g = c*r - bq;
                w2 = c; w5 = s;
              }
              { // i=3
                float f = s*e3, bq = c*e3;
                slartgf(g, f, &c, &s, &r);
                e2 = r;
                g = d3 - p;
                r = (d4 - g)*s + (2.0f*c)*bq;
                p = s*r;
                d3 = g + p;
                g = c*r - bq;
                w3 = c; w6 = s;
              }
              if (w2 != 1.0f || w5 != 0.0f) ROTZ(3, w2, w5);
              if (w3 != 1.0f || w6 != 0.0f) ROTZ(4, w3, w6);
              d4 = d4 - p;
              e3 = g;
            } else {
              // defensive fallback: original dynamic text
              g = (RD_D(l-1) - p) / (2.0f*RD_E(l-1));
              r = slapy2f(g, 1.0f);
              g = RD_D(m2) - p + (RD_E(l-1) / (g + copysignf(r, g)));
              s = 1.0f; c = 1.0f;
              p = 0.0f;
              for (int i = m2; i <= l-1; i++){
                float f  = s*RD_E(i);
                float bq = c*RD_E(i);
                slartgf(g, f, &c, &s, &r);
                if (i != m2) WR_E(i-1, r);
                g = RD_D(i) - p;
                r = (RD_D(i+1) - g)*s + (2.0f*c)*bq;
                p = s*r;
                WR_D(i, g + p);
                g = c*r - bq;
                WR_W(i, c);
                WR_W(3+i, s);
              }
              int mmn = l - m2 + 1;    // slasr('R','V','F')
              for (int j = 1; j <= mmn-1; j++){
                float ct = RD_W(m2+j-1), sx = RD_W(3+m2+j-1);
                if (ct != 1.0f || sx != 0.0f) ROTZ(m2+j, ct, sx);
              }
              WR_D(l, RD_D(l) - p);
              WR_E(l-1, g);
            }
          }
        }
      }
      if (jtot >= nmaxit) break;
    }
  }

  // argmin eigenvalue (first minimum — matches ssteqr selection-sort rank-0 pick)
  int kbest = 1;
  float dmin = d1;
  if (d2 < dmin){ dmin = d2; kbest = 2; }
  if (d3 < dmin){ dmin = d3; kbest = 3; }
  if (d4 < dmin){ dmin = d4; kbest = 4; }
  float zc1 = RD_Z(1,kbest);
  float zc2 = RD_Z(2,kbest);
  float zc3 = RD_Z(3,kbest);
  float zc4 = RD_Z(4,kbest);

  // sormtr: apply Q = H1*H2 (H2 first, then H1); H3 has tau=0
  {
    float v2 = A[4][2];
    float sum = zc3 + v2*zc4;
    float tt = tauv[2]*sum;
    zc3 = zc3 - tt;
    zc4 = zc4 - tt*v2;
  }
  {
    float va = A[3][1], vb = A[4][1];
    float sum = zc2 + va*zc3;
    sum = sum + vb*zc4;
    float tt = tauv[1]*sum;
    zc2 = zc2 - tt;
    zc3 = zc3 - tt*va;
    zc4 = zc4 - tt*vb;
  }

  // reference post-process: normalize by ||(a,b,c)||, sign-fix abc only
  float n2 = zc1*zc1;
  n2 = n2 + zc2*zc2;
  n2 = n2 + zc3*zc3;
  float nrm = sqrtf(n2);
  float a0 = zc1/nrm;
  float b0 = zc2/nrm;
  float c0 = zc3/nrm;
  float d0 = zc4/nrm;
  float sg = (b0 < 0.0f) ? -1.0f : 1.0f;
  a0 = a0*sg; b0 = b0*sg; c0 = c0*sg;

  if (threadIdx.x == 0){
    float* mp = &models[(size_t)t*4];
    mp[0]=a0; mp[1]=b0; mp[2]=c0; mp[3]=d0;
  }
}

// ---------------- Kernel 2: inlier counting (R6/R8-proven body) + fused last-block scan ----------------
// Count body verbatim R6/R8/R10. After the count atomics, each block arrives
// at a device-scope counter (zeroed by the stream-ordered models dispatch);
// the LAST arriving block runs the R4-proven scan text (strides adapted
// 64->256; per-slot logic identical). counts are read with
// __hip_atomic_load(AGENT) to bypass potentially-stale per-XCD caches (G16).
// No spin-waits => no deadlock; deterministic; state re-zeroed every launch.

__global__ void __launch_bounds__(256) count_scan_kernel(const float* __restrict__ data,
                                                         const float* __restrict__ models,
                                                         int* __restrict__ counts,
                                                         int* __restrict__ done,
                                                         float* __restrict__ out){
  const int g = blockIdx.x % NGRP;       // model group 0..4
  const int c = blockIdx.x / NGRP;       // point chunk 0..7 (4096 pts each)
  const int b = blockIdx.y;              // batch 0..31
  const int tid = (int)threadIdx.x;

  float4 mv[MGRP];
  #pragma unroll
  for (int j=0;j<MGRP;j++)
    mv[j] = ((const float4*)models)[(g*MGRP + j)*BB + b];   // uniform (broadcast)

  const float* dp = data + (size_t)b*NPTS*3 + (size_t)c*4096*3;
  int cnt[MGRP];
  #pragma unroll
  for (int j=0;j<MGRP;j++) cnt[j] = 0;

  #pragma unroll
  for (int i=0;i<4;i++){
    // thread handles 4 consecutive points: base float offset 12*(i*256+tid), 48B-aligned
    const float4* q = (const float4*)(dp + 12*(i*256 + tid));
    float4 f0 = q[0];
    float4 f1 = q[1];
    float4 f2 = q[2];
    float px[4], py[4], pz[4];
    px[0]=f0.x; py[0]=f0.y; pz[0]=f0.z;
    px[1]=f0.w; py[1]=f1.x; pz[1]=f1.y;
    px[2]=f1.z; py[2]=f1.w; pz[2]=f2.x;
    px[3]=f2.y; py[3]=f2.z; pz[3]=f2.w;
    #pragma unroll
    for (int j=0;j<MGRP;j++){
      #pragma unroll
      for (int k=0;k<4;k++){
        // numpy einsum order, separate rounding (no FMA): ((a*x + b*y) + c*z) + d
        float sv = __fmul_rn(mv[j].x, px[k]);
        sv = __fadd_rn(sv, __fmul_rn(mv[j].y, py[k]));
        sv = __fadd_rn(sv, __fmul_rn(mv[j].z, pz[k]));
        sv = __fadd_rn(sv, mv[j].w);
        cnt[j] += (int)__popcll(__ballot(fabsf(sv) < 0.05f));
      }
    }
  }
  // wave-uniform counts (ballot); one atomicAdd per wave per model
  if ((tid & 63) == 0){
    #pragma unroll
    for (int j=0;j<MGRP;j++)
      atomicAdd(&counts[(g*MGRP + j)*BB + b], cnt[j]);
  }

  // ---- arrival: last block to finish runs the scan ----
  __shared__ int s_last;
  __syncthreads();                       // all waves' count atomics issued & drained (waitcnt before barrier)
  if (tid == 0){
    __threadfence();                     // release: order count atomics before arrival
    int old = atomicAdd(done, 1);
    s_last = (old == CBLOCKS-1) ? 1 : 0;
  }
  __syncthreads();
  if (s_last == 0) return;

  // ---- scan + output (R4-proven logic; 256 threads; coherent count reads) ----
  __shared__ int   icarr[NIT*BB];
  __shared__ int   pmarr[NIT*BB];
  __shared__ float karr[NIT*BB];
  __shared__ int   sdone[NIT];
  __shared__ int   sistop;
  for (int t2 = tid; t2 < NIT*BB; t2 += 256)
    icarr[t2] = __hip_atomic_load(&counts[t2], __ATOMIC_RELAXED, __HIP_MEMORY_SCOPE_AGENT);
  __syncthreads();
  if (tid < BB){
    int pm = 0;
    for (int it=0; it<NIT; it++){
      int ic = icarr[it*BB + tid];
      pm = (ic > pm) ? ic : pm;
      pmarr[it*BB + tid] = pm;
    }
  }
  __syncthreads();
  for (int t2 = tid; t2 < NIT*BB; t2 += 256){
    float p = (float)pmarr[t2] / 32768.0f;
    float p3 = (p*p)*p;
    float prob = fminf(1.0f - p3, 0.99f);
    karr[t2] = -0.35667494393873245f / (logf(prob) + 1e-10f);
  }
  __syncthreads();
  if (tid < NIT){
    float kmax = karr[tid*BB];
    for (int bb=1;bb<BB;bb++) kmax = fmaxf(kmax, karr[tid*BB + bb]);
    int reason = (int)kmax;            // astype(int32): trunc toward zero
    if (reason > 100) reason = 100;
    sdone[tid] = ((tid+1) >= reason) ? 1 : 0;
  }
  __syncthreads();
  if (tid == 0){
    int is = NIT-1;                    // guaranteed hit at it<=34 (reason<=35)
    for (int it=0; it<NIT; it++){ if (sdone[it]){ is = it; break; } }
    sistop = is;
  }
  __syncthreads();
  if (tid < BB){
    const int istop = sistop;
    int best = 0, bit = -1;
    for (int it=0; it<=istop; it++){
      int ic = icarr[it*BB + tid];
      if (ic > best){ best = ic; bit = it; }
    }
    float4 m = make_float4(0.0f,0.0f,0.0f,0.0f);
    if (bit >= 0) m = ((const float4*)models)[bit*BB + tid];
    ((float4*)out)[tid] = m;
  }
}

// ---------------- launch ----------------

extern "C" void kernel_launch(void* const* d_in, const int* in_sizes, int n_in,
                              void* d_out, int out_size, void* d_ws, size_t ws_size,
                              hipStream_t stream){
  const float* data = (const float*)d_in[0];
  const int*   idx  = (const int*)d_in[1];
  float* out = (float*)d_out;
  float* models = (float*)d_ws;                                        // NIT*32*4 floats
  int*   counts = (int*)((char*)d_ws + (size_t)NIT*BB*4*sizeof(float)); // NIT*32 ints
  int*   done   = counts + NIT*BB;                                     // 1 int arrival counter

  models_kernel<<<NIT*BB, 64, 0, stream>>>(data, idx, models, counts, done);
  count_scan_kernel<<<dim3(NGRP*8, BB), 256, 0, stream>>>(data, models, counts, done, out);
}

// Round 12
// 104.029 us; speedup vs baseline: 1.1696x; 1.1696x over previous
//
#include <hip/hip_runtime.h>
#include <math.h>

// Match x86 reference LAPACK (no FMA contraction anywhere in the emulation).
#pragma clang fp contract(off)

#define NIT 35      // provable: prob=min(...,0.99)<=0.99 => k<=35.49 => reason<=35 => no update past it=34
#define BB  32
#define NPTS 32768
#define MGRP 7      // models per count-block
#define NGRP 5      // NIT = MGRP * NGRP
#define CBLOCKS (NGRP*8*BB)   // 1280 count blocks

// ---------------- LAPACK helpers (fp32, faithful) ----------------

__device__ __forceinline__ float slapy2f(float x, float y){
  float xa = fabsf(x), ya = fabsf(y);
  float w = fmaxf(xa, ya), z = fminf(xa, ya);
  if (z == 0.0f) return w;
  float q = z / w;
  return w * sqrtf(1.0f + q*q);
}

// LAPACK >= 3.10 slartg (modern OpenBLAS as shipped with numpy/scipy).
__device__ __forceinline__ void slartgf(float f, float g, float* cs, float* sn, float* r){
  if (g == 0.0f){ *cs = 1.0f; *sn = 0.0f; *r = f; return; }
  if (f == 0.0f){ *cs = 0.0f; *sn = copysignf(1.0f, g); *r = fabsf(g); return; }
  float f1 = fabsf(f);
  float d  = sqrtf(f*f + g*g);
  *cs = f1 / d;
  *r  = copysignf(d, f);
  *sn = g / (*r);
}

__device__ void slaev2f(float a, float b, float c,
                        float* rt1, float* rt2, float* cs1, float* sn1){
  float sm  = a + c;
  float df  = a - c;
  float adf = fabsf(df);
  float tb  = b + b;
  float ab  = fabsf(tb);
  float acmx, acmn;
  if (fabsf(a) > fabsf(c)){ acmx = a; acmn = c; } else { acmx = c; acmn = a; }
  float rt;
  if (adf > ab){ float q = ab/adf; rt = adf*sqrtf(1.0f + q*q); }
  else if (adf < ab){ float q = adf/ab; rt = ab*sqrtf(1.0f + q*q); }
  else rt = ab*sqrtf(2.0f);
  int sgn1;
  if (sm < 0.0f){
    *rt1 = 0.5f*(sm - rt); sgn1 = -1;
    *rt2 = (acmx / *rt1)*acmn - (b / *rt1)*b;
  } else if (sm > 0.0f){
    *rt1 = 0.5f*(sm + rt); sgn1 = 1;
    *rt2 = (acmx / *rt1)*acmn - (b / *rt1)*b;
  } else {
    *rt1 = 0.5f*rt; *rt2 = -0.5f*rt; sgn1 = 1;
  }
  float cs; int sgn2;
  if (df >= 0.0f){ cs = df + rt; sgn2 = 1; } else { cs = df - rt; sgn2 = -1; }
  float acs = fabsf(cs);
  float cs1v, sn1v;
  if (acs > ab){
    float ct = -tb/cs;
    sn1v = 1.0f/sqrtf(1.0f + ct*ct);
    cs1v = ct*sn1v;
  } else {
    if (ab == 0.0f){ cs1v = 1.0f; sn1v = 0.0f; }
    else {
      float tn = -cs/tb;
      cs1v = 1.0f/sqrtf(1.0f + tn*tn);
      sn1v = tn*cs1v;
    }
  }
  if (sgn1 == sgn2){ float t = cs1v; cs1v = -sn1v; sn1v = t; }
  *cs1 = cs1v; *sn1 = sn1v;
}

// ---- register-resident dynamic access (R2-proven text) — cold paths only ----
#define RD_D(i)   ((i)==1?d1:(i)==2?d2:(i)==3?d3:d4)
#define WR_D(i,v) do{ float _v=(v); int _ix=(i); if(_ix==1)d1=_v; else if(_ix==2)d2=_v; else if(_ix==3)d3=_v; else d4=_v; }while(0)
#define RD_E(i)   ((i)==1?e1:(i)==2?e2:(i)==3?e3:e4)
#define WR_E(i,v) do{ float _v=(v); int _ix=(i); if(_ix==1)e1=_v; else if(_ix==2)e2=_v; else if(_ix==3)e3=_v; else e4=_v; }while(0)
#define RD_W(i)   ((i)==1?w1:(i)==2?w2:(i)==3?w3:(i)==4?w4:(i)==5?w5:(i)==6?w6:w7)
#define WR_W(i,v) do{ float _v=(v); int _ix=(i); if(_ix==1)w1=_v; else if(_ix==2)w2=_v; else if(_ix==3)w3=_v; else if(_ix==4)w4=_v; else if(_ix==5)w5=_v; else if(_ix==6)w6=_v; else w7=_v; }while(0)
#define RD_Z(i,j) ((j)==1? z##i##1 : (j)==2? z##i##2 : (j)==3? z##i##3 : z##i##4)
#define WR_Z(i,j,v) do{ float _vv=(v); int _jj=(j); \
  if(_jj==1) z##i##1=_vv; else if(_jj==2) z##i##2=_vv; else if(_jj==3) z##i##3=_vv; else z##i##4=_vv; }while(0)
#define ROTZ_ROW(i,jv,cv,sv) do{ \
  float _t = RD_Z(i,(jv)); float _o = RD_Z(i,(jv)-1); \
  float _nt = (cv)*_t - (sv)*_o; \
  float _no = (sv)*_t + (cv)*_o; \
  WR_Z(i,(jv),_nt); WR_Z(i,(jv)-1,_no); \
}while(0)
#define ROTZ(jv,cv,sv) do{ int _rj=(jv); float _rc=(cv), _rs=(sv); \
  ROTZ_ROW(1,_rj,_rc,_rs); ROTZ_ROW(2,_rj,_rc,_rs); ROTZ_ROW(3,_rj,_rc,_rs); ROTZ_ROW(4,_rj,_rc,_rs); }while(0)

// ---------------- Kernel 1: one (it,b) problem per WAVE (verbatim R10-proven) ----------------

__global__ void __launch_bounds__(64) models_kernel(const float* __restrict__ data,
                                                    const int* __restrict__ idx,
                                                    float* __restrict__ models,
                                                    int* __restrict__ counts,
                                                    int* __restrict__ done){
  const int t = blockIdx.x;              // 0..NIT*BB-1; all 64 lanes compute redundantly
  if (threadIdx.x == 0){
    counts[t] = 0;                       // count dispatch is later; stream order safe
    if (t == 0) *done = 0;               // arrival counter for fused count+scan
  }
  const int it = t >> 5;
  const int b  = t & 31;

  // gather 3 samples, aug rows [x,y,z,1]
  float P[3][4];
  const int* ip = &idx[(it*BB + b)*3];
  #pragma unroll
  for (int s=0;s<3;s++){
    int n = ip[s];
    const float* pp = &data[((long)b*NPTS + n)*3];
    P[s][0]=pp[0]; P[s][1]=pp[1]; P[s][2]=pp[2]; P[s][3]=1.0f;
  }
  // A = aug^T aug (sum over s in order 0,1,2; separate rounding)
  float A[5][5];
  #pragma unroll
  for (int i=0;i<4;i++)
    #pragma unroll
    for (int j=0;j<4;j++){
      float acc = P[0][i]*P[0][j];
      acc = acc + P[1][i]*P[1][j];
      acc = acc + P[2][i]*P[2][j];
      A[i+1][j+1] = acc;
    }

  // ssytd2 (UPLO='L', n=4): reference-BLAS op ordering
  float eE[5], tauv[4];
  #pragma unroll
  for (int i=1;i<=3;i++){
    float alpha = A[i+1][i];
    float ssq = 0.0f;
    #pragma unroll
    for (int k=i+2;k<=4;k++) ssq = ssq + A[k][i]*A[k][i];
    float xnorm = sqrtf(ssq);
    float taui;
    if (xnorm == 0.0f){
      taui = 0.0f;
    } else {
      float beta = -copysignf(slapy2f(alpha, xnorm), alpha);
      taui = (beta - alpha)/beta;
      float sc = 1.0f/(alpha - beta);
      #pragma unroll
      for (int k=i+2;k<=4;k++) A[k][i] = A[k][i]*sc;
      alpha = beta;
    }
    eE[i] = alpha;
    if (taui != 0.0f){
      A[i+1][i] = 1.0f;
      float w[5];
      #pragma unroll
      for (int r=i+1;r<=4;r++) w[r] = 0.0f;
      // ssymv('L'): w = taui * Asub * v
      #pragma unroll
      for (int j=i+1;j<=4;j++){
        float temp1 = taui*A[j][i];
        float temp2 = 0.0f;
        w[j] = w[j] + temp1*A[j][j];
        #pragma unroll
        for (int r=j+1;r<=4;r++){
          w[r] = w[r] + temp1*A[r][j];
          temp2 = temp2 + A[r][j]*A[r][i];
        }
        w[j] = w[j] + taui*temp2;
      }
      float dot = 0.0f;
      #pragma unroll
      for (int r=i+1;r<=4;r++) dot = dot + w[r]*A[r][i];
      float alpha2 = (-0.5f*taui)*dot;
      #pragma unroll
      for (int r=i+1;r<=4;r++) w[r] = w[r] + alpha2*A[r][i];
      // ssyr2('L', alpha=-1)
      #pragma unroll
      for (int j=i+1;j<=4;j++){
        float xj = A[j][i], yj = w[j];
        if (xj != 0.0f || yj != 0.0f){
          float temp1 = -yj;
          float temp2 = -xj;
          #pragma unroll
          for (int r=j;r<=4;r++){
            float acc = A[r][j] + A[r][i]*temp1;
            acc = acc + w[r]*temp2;
            A[r][j] = acc;
          }
        }
      }
    }
    tauv[i] = taui;
  }

  // ---------------- ssteqr('I', n=4), all state in registers ----------------
  float d1=A[1][1], d2=A[2][2], d3=A[3][3], d4=A[4][4];
  float e1=eE[1], e2=eE[2], e3=eE[3], e4=0.0f;
  float w1=0,w2=0,w3=0,w4=0,w5=0,w6=0,w7=0;
  float z11=1,z12=0,z13=0,z14=0;
  float z21=0,z22=1,z23=0,z24=0;
  float z31=0,z32=0,z33=1,z34=0;
  float z41=0,z42=0,z43=0,z44=1;
  (void)e4; (void)w7;

  {
    const float eps    = 5.9604645e-08f;
    const float eps2   = eps*eps;
    const float safmin = 1.17549435e-38f;
    const int nmaxit = 4*30;
    int jtot = 0;

    int l1 = 1;
    while (l1 <= 4){
      if (l1 > 1) WR_E(l1-1, 0.0f);
      // ---- outer m-scan, statically unrolled on l1 (R8-proven) ----
      int m = 4;
      do {
        if (l1 == 1){
          float tst = fabsf(e1);
          if (tst == 0.0f){ m = 1; break; }
          if (tst <= (sqrtf(fabsf(d1)) * sqrtf(fabsf(d2))) * eps){ e1 = 0.0f; m = 1; break; }
        }
        if (l1 <= 2){
          float tst = fabsf(e2);
          if (tst == 0.0f){ m = 2; break; }
          if (tst <= (sqrtf(fabsf(d2)) * sqrtf(fabsf(d3))) * eps){ e2 = 0.0f; m = 2; break; }
        }
        if (l1 <= 3){
          float tst = fabsf(e3);
          if (tst == 0.0f){ m = 3; break; }
          if (tst <= (sqrtf(fabsf(d3)) * sqrtf(fabsf(d4))) * eps){ e3 = 0.0f; m = 3; break; }
        }
      } while(0);
      int l = l1, lsv = l, lend = m, lendsv = lend;
      l1 = m + 1;
      if (lend == l) continue;

      // ---- anorm + direction swap, statically specialized (R10-proven) ----
      {
        float anorm; bool sw;
        if (l == 1){
          if (lend == 2){
            anorm = fmaxf(fmaxf(0.0f, fabsf(d1)), fabsf(d2));
            anorm = fmaxf(anorm, fabsf(e1));
            sw = fabsf(d2) < fabsf(d1);
          } else if (lend == 3){
            anorm = fmaxf(fmaxf(fmaxf(0.0f, fabsf(d1)), fabsf(d2)), fabsf(d3));
            anorm = fmaxf(fmaxf(anorm, fabsf(e1)), fabsf(e2));
            sw = fabsf(d3) < fabsf(d1);
          } else {
            anorm = fmaxf(fmaxf(fmaxf(fmaxf(0.0f, fabsf(d1)), fabsf(d2)), fabsf(d3)), fabsf(d4));
            anorm = fmaxf(fmaxf(fmaxf(anorm, fabsf(e1)), fabsf(e2)), fabsf(e3));
            sw = fabsf(d4) < fabsf(d1);
          }
        } else if (l == 2){
          if (lend == 3){
            anorm = fmaxf(fmaxf(0.0f, fabsf(d2)), fabsf(d3));
            anorm = fmaxf(anorm, fabsf(e2));
            sw = fabsf(d3) < fabsf(d2);
          } else {
            anorm = fmaxf(fmaxf(fmaxf(0.0f, fabsf(d2)), fabsf(d3)), fabsf(d4));
            anorm = fmaxf(fmaxf(anorm, fabsf(e2)), fabsf(e3));
            sw = fabsf(d4) < fabsf(d2);
          }
        } else { // l==3, lend==4
          anorm = fmaxf(fmaxf(0.0f, fabsf(d3)), fabsf(d4));
          anorm = fmaxf(anorm, fabsf(e3));
          sw = fabsf(d4) < fabsf(d3);
        }
        if (anorm == 0.0f) continue;
        if (sw){ lend = lsv; l = lendsv; }
      }

      if (lend > l){
        // ---------------- QL iteration ----------------
        for(;;){
          // ---- inner deflation scan, statically unrolled (R8-proven) ----
          int m2 = lend;
          if (l != lend){
            do {
              if (l <= 1){                    // mm=1 (lend>=2 since lend>l)
                float tst = e1*e1;
                if (tst <= (eps2*fabsf(d1))*fabsf(d2) + safmin){ m2 = 1; break; }
              }
              if (l <= 2 && lend >= 3){       // mm=2
                float tst = e2*e2;
                if (tst <= (eps2*fabsf(d2))*fabsf(d3) + safmin){ m2 = 2; break; }
              }
              if (l <= 3 && lend >= 4){       // mm=3
                float tst = e3*e3;
                if (tst <= (eps2*fabsf(d3))*fabsf(d4) + safmin){ m2 = 3; break; }
              }
            } while(0);
          }
          if (m2 < lend) WR_E(m2, 0.0f);
          float p = RD_D(l);
          if (m2 == l){
            WR_D(l, p); l = l + 1;
            if (l <= lend) continue;
            break;
          }
          if (m2 == l+1){
            float rt1, rt2, c1, s1;
            if (l == 1){
              slaev2f(d1, e1, d2, &rt1, &rt2, &c1, &s1);
              w1 = c1; w4 = s1;
              ROTZ(2, c1, s1);
              d1 = rt1; d2 = rt2; e1 = 0.0f;
            } else if (l == 2){
              slaev2f(d2, e2, d3, &rt1, &rt2, &c1, &s1);
              w2 = c1; w5 = s1;
              ROTZ(3, c1, s1);
              d2 = rt1; d3 = rt2; e2 = 0.0f;
            } else {
              slaev2f(d3, e3, d4, &rt1, &rt2, &c1, &s1);
              w3 = c1; w6 = s1;
              ROTZ(4, c1, s1);
              d3 = rt1; d4 = rt2; e3 = 0.0f;
            }
            l = l + 2;
            if (l <= lend) continue;
            break;
          }
          if (jtot == nmaxit) break;
          jtot++;
          {
            float g, r, s = 1.0f, c = 1.0f;
            if (l == 1 && m2 == 3){
              g = (d2 - p) / (2.0f*e1);
              r = slapy2f(g, 1.0f);
              g = d3 - p + (e1 / (g + copysignf(r, g)));
              p = 0.0f;
              { // i=2 (first: no e-write)
                float f = s*e2, bq = c*e2;
                slartgf(g, f, &c, &s, &r);
                g = d3 - p;
                r = (d2 - g)*s + (2.0f*c)*bq;
                p = s*r;
                d3 = g + p;
                g = c*r - bq;
                w2 = c; w5 = -s;
              }
              { // i=1
                float f = s*e1, bq = c*e1;
                slartgf(g, f, &c, &s, &r);
                e2 = r;
                g = d2 - p;
                r = (d1 - g)*s + (2.0f*c)*bq;
                p = s*r;
                d2 = g + p;
                g = c*r - bq;
                w1 = c; w4 = -s;
              }
              if (w2 != 1.0f || w5 != 0.0f) ROTZ(3, w2, w5);
              if (w1 != 1.0f || w4 != 0.0f) ROTZ(2, w1, w4);
              d1 = d1 - p;
              e1 = g;
            } else if (l == 1 && m2 == 4){
              g = (d2 - p) / (2.0f*e1);
              r = slapy2f(g, 1.0f);
              g = d4 - p + (e1 / (g + copysignf(r, g)));
              p = 0.0f;
              { // i=3 (first)
                float f = s*e3, bq = c*e3;
                slartgf(g, f, &c, &s, &r);
                g = d4 - p;
                r = (d3 - g)*s + (2.0f*c)*bq;
                p = s*r;
                d4 = g + p;
                g = c*r - bq;
                w3 = c; w6 = -s;
              }
              { // i=2
                float f = s*e2, bq = c*e2;
                slartgf(g, f, &c, &s, &r);
                e3 = r;
                g = d3 - p;
                r = (d2 - g)*s + (2.0f*c)*bq;
                p = s*r;
                d3 = g + p;
                g = c*r - bq;
                w2 = c; w5 = -s;
              }
              { // i=1
                float f = s*e1, bq = c*e1;
                slartgf(g, f, &c, &s, &r);
                e2 = r;
                g = d2 - p;
                r = (d1 - g)*s + (2.0f*c)*bq;
                p = s*r;
                d2 = g + p;
                g = c*r - bq;
                w1 = c; w4 = -s;
              }
              if (w3 != 1.0f || w6 != 0.0f) ROTZ(4, w3, w6);
              if (w2 != 1.0f || w5 != 0.0f) ROTZ(3, w2, w5);
              if (w1 != 1.0f || w4 != 0.0f) ROTZ(2, w1, w4);
              d1 = d1 - p;
              e1 = g;
            } else if (l == 2 && m2 == 4){
              g = (d3 - p) / (2.0f*e2);
              r = slapy2f(g, 1.0f);
              g = d4 - p + (e2 / (g + copysignf(r, g)));
              p = 0.0f;
              { // i=3 (first)
                float f = s*e3, bq = c*e3;
                slartgf(g, f, &c, &s, &r);
                g = d4 - p;
                r = (d3 - g)*s + (2.0f*c)*bq;
                p = s*r;
                d4 = g + p;
                g = c*r - bq;
                w3 = c; w6 = -s;
              }
              { // i=2
                float f = s*e2, bq = c*e2;
                slartgf(g, f, &c, &s, &r);
                e3 = r;
                g = d3 - p;
                r = (d2 - g)*s + (2.0f*c)*bq;
                p = s*r;
                d3 = g + p;
                g = c*r - bq;
                w2 = c; w5 = -s;
              }
              if (w3 != 1.0f || w6 != 0.0f) ROTZ(4, w3, w6);
              if (w2 != 1.0f || w5 != 0.0f) ROTZ(3, w2, w5);
              d2 = d2 - p;
              e2 = g;
            } else {
              // defensive fallback: original dynamic text
              g = (RD_D(l+1) - p) / (2.0f*RD_E(l));
              r = slapy2f(g, 1.0f);
              g = RD_D(m2) - p + (RD_E(l) / (g + copysignf(r, g)));
              s = 1.0f; c = 1.0f;
              p = 0.0f;
              for (int i = m2-1; i >= l; i--){
                float f  = s*RD_E(i);
                float bq = c*RD_E(i);
                slartgf(g, f, &c, &s, &r);
                if (i != m2-1) WR_E(i+1, r);
                g = RD_D(i+1) - p;
                r = (RD_D(i) - g)*s + (2.0f*c)*bq;
                p = s*r;
                WR_D(i+1, g + p);
                g = c*r - bq;
                WR_W(i, c);
                WR_W(3+i, -s);
              }
              int mmn = m2 - l + 1;    // slasr('R','V','B')
              for (int j = mmn-1; j >= 1; j--){
                float ct = RD_W(l+j-1), sx = RD_W(3+l+j-1);
                if (ct != 1.0f || sx != 0.0f) ROTZ(l+j, ct, sx);
              }
              WR_D(l, RD_D(l) - p);
              WR_E(l, g);
            }
          }
        }
      } else {
        // ---------------- QR iteration ----------------
        for(;;){
          // ---- inner deflation scan, statically unrolled (R8-proven) ----
          int m2 = lend;
          if (l != lend){
            do {
              if (l >= 4){                    // mm=4 (lend<=3 since lend<l)
                float tst = e3*e3;
                if (tst <= (eps2*fabsf(d4))*fabsf(d3) + safmin){ m2 = 4; break; }
              }
              if (l >= 3 && lend <= 2){       // mm=3
                float tst = e2*e2;
                if (tst <= (eps2*fabsf(d3))*fabsf(d2) + safmin){ m2 = 3; break; }
              }
              if (l >= 2 && lend <= 1){       // mm=2
                float tst = e1*e1;
                if (tst <= (eps2*fabsf(d2))*fabsf(d1) + safmin){ m2 = 2; break; }
              }
            } while(0);
          }
          if (m2 > lend) WR_E(m2-1, 0.0f);
          float p = RD_D(l);
          if (m2 == l){
            WR_D(l, p); l = l - 1;
            if (l >= lend) continue;
            break;
          }
          if (m2 == l-1){
            float rt1, rt2, c1, s1;
            if (l == 2){
              slaev2f(d1, e1, d2, &rt1, &rt2, &c1, &s1);
              w1 = c1; w4 = s1;
              ROTZ(2, c1, s1);
              d1 = rt1; d2 = rt2; e1 = 0.0f;
            } else if (l == 3){
              slaev2f(d2, e2, d3, &rt1, &rt2, &c1, &s1);
              w2 = c1; w5 = s1;
              ROTZ(3, c1, s1);
              d2 = rt1; d3 = rt2; e2 = 0.0f;
            } else {
              slaev2f(d3, e3, d4, &rt1, &rt2, &c1, &s1);
              w3 = c1; w6 = s1;
              ROTZ(4, c1, s1);
              d3 = rt1; d4 = rt2; e3 = 0.0f;
            }
            l = l - 2;
            if (l >= lend) continue;
            break;
          }
          if (jtot == nmaxit) break;
          jtot++;
          {
            float g, r, s = 1.0f, c = 1.0f;
            if (l == 3 && m2 == 1){
              g = (d2 - p) / (2.0f*e2);
              r = slapy2f(g, 1.0f);
              g = d1 - p + (e2 / (g + copysignf(r, g)));
              p = 0.0f;
              { // i=1 (first: no e-write)
                float f = s*e1, bq = c*e1;
                slartgf(g, f, &c, &s, &r);
                g = d1 - p;
                r = (d2 - g)*s + (2.0f*c)*bq;
                p = s*r;
                d1 = g + p;
                g = c*r - bq;
                w1 = c; w4 = s;
              }
              { // i=2
                float f = s*e2, bq = c*e2;
                slartgf(g, f, &c, &s, &r);
                e1 = r;
                g = d2 - p;
                r = (d3 - g)*s + (2.0f*c)*bq;
                p = s*r;
                d2 = g + p;
                g = c*r - bq;
                w2 = c; w5 = s;
              }
              if (w1 != 1.0f || w4 != 0.0f) ROTZ(2, w1, w4);
              if (w2 != 1.0f || w5 != 0.0f) ROTZ(3, w2, w5);
              d3 = d3 - p;
              e2 = g;
            } else if (l == 4 && m2 == 1){
              g = (d3 - p) / (2.0f*e3);
              r = slapy2f(g, 1.0f);
              g = d1 - p + (e3 / (g + copysignf(r, g)));
              p = 0.0f;
              { // i=1 (first)
                float f = s*e1, bq = c*e1;
                slartgf(g, f, &c, &s, &r);
                g = d1 - p;
                r = (d2 - g)*s + (2.0f*c)*bq;
                p = s*r;
                d1 = g + p;
                g = c*r - bq;
                w1 = c; w4 = s;
              }
              { // i=2
                float f = s*e2, bq = c*e2;
                slartgf(g, f, &c, &s, &r);
                e1 = r;
                g = d2 - p;
                r = (d3 - g)*s + (2.0f*c)*bq;
                p = s*r;
                d2 = g + p;
                g = c*r - bq;
                w2 = c; w5 = s;
              }
              { // i=3
                float f = s*e3, bq = c*e3;
                slartgf(g, f, &c, &s, &r);
                e2 = r;
                g = d3 - p;
                r = (d4 - g)*s + (2.0f*c)*bq;
                p = s*r;
                d3 = g + p;
                g = c*r - bq;
                w3 = c; w6 = s;
              }
              if (w1 != 1.0f || w4 != 0.0f) ROTZ(2, w1, w4);
              if (w2 != 1.0f || w5 != 0.0f) ROTZ(3, w2, w5);
              if (w3 != 1.0f || w6 != 0.0f) ROTZ(4, w3, w6);
              d4 = d4 - p;
              e3 = g;
            } else if (l == 4 && m2 == 2){
              g = (d3 - p) / (2.0f*e3);
              r = slapy2f(g, 1.0f);
              g = d2 - p + (e3 / (g + copysignf(r, g)));
              p = 0.0f;
              { // i=2 (first)
                float f = s*e2, bq = c*e2;
                slartgf(g, f, &c, &s, &r);
                g = d2 - p;
                r = (d3 - g)*s + (2.0f*c)*bq;
                p = s*r;
                d2 = g + p;
                g = c*r - bq;
                w2 = c; w5 = s;
              }
              { // i=3
                float f = s*e3, bq = c*e3;
                slartgf(g, f, &c, &s, &r);
                e2 = r;
                g = d3 - p;
                r = (d4 - g)*s + (2.0f*c)*bq;
                p = s*r;
                d3 = g + p;
                g = c*r - bq;
                w3 = c; w6 = s;
              }
              if (w2 != 1.0f || w5 != 0.0f) ROTZ(3, w2, w5);
              if (w3 != 1.0f || w6 != 0.0f) ROTZ(4, w3, w6);
              d4 = d4 - p;
              e3 = g;
            } else {
              // defensive fallback: original dynamic text
              g = (RD_D(l-1) - p) / (2.0f*RD_E(l-1));
              r = slapy2f(g, 1.0f);
              g = RD_D(m2) - p + (RD_E(l-1) / (g + copysignf(r, g)));
              s = 1.0f; c = 1.0f;
              p = 0.0f;
              for (int i = m2; i <= l-1; i++){
                float f  = s*RD_E(i);
                float bq = c*RD_E(i);
                slartgf(g, f, &c, &s, &r);
                if (i != m2) WR_E(i-1, r);
                g = RD_D(i) - p;
                r = (RD_D(i+1) - g)*s + (2.0f*c)*bq;
                p = s*r;
                WR_D(i, g + p);
                g = c*r - bq;
                WR_W(i, c);
                WR_W(3+i, s);
              }
              int mmn = l - m2 + 1;    // slasr('R','V','F')
              for (int j = 1; j <= mmn-1; j++){
                float ct = RD_W(m2+j-1), sx = RD_W(3+m2+j-1);
                if (ct != 1.0f || sx != 0.0f) ROTZ(m2+j, ct, sx);
              }
              WR_D(l, RD_D(l) - p);
              WR_E(l-1, g);
            }
          }
        }
      }
      if (jtot >= nmaxit) break;
    }
  }

  // argmin eigenvalue (first minimum — matches ssteqr selection-sort rank-0 pick)
  int kbest = 1;
  float dmin = d1;
  if (d2 < dmin){ dmin = d2; kbest = 2; }
  if (d3 < dmin){ dmin = d3; kbest = 3; }
  if (d4 < dmin){ dmin = d4; kbest = 4; }
  float zc1 = RD_Z(1,kbest);
  float zc2 = RD_Z(2,kbest);
  float zc3 = RD_Z(3,kbest);
  float zc4 = RD_Z(4,kbest);

  // sormtr: apply Q = H1*H2 (H2 first, then H1); H3 has tau=0
  {
    float v2 = A[4][2];
    float sum = zc3 + v2*zc4;
    float tt = tauv[2]*sum;
    zc3 = zc3 - tt;
    zc4 = zc4 - tt*v2;
  }
  {
    float va = A[3][1], vb = A[4][1];
    float sum = zc2 + va*zc3;
    sum = sum + vb*zc4;
    float tt = tauv[1]*sum;
    zc2 = zc2 - tt;
    zc3 = zc3 - tt*va;
    zc4 = zc4 - tt*vb;
  }

  // reference post-process: normalize by ||(a,b,c)||, sign-fix abc only
  float n2 = zc1*zc1;
  n2 = n2 + zc2*zc2;
  n2 = n2 + zc3*zc3;
  float nrm = sqrtf(n2);
  float a0 = zc1/nrm;
  float b0 = zc2/nrm;
  float c0 = zc3/nrm;
  float d0 = zc4/nrm;
  float sg = (b0 < 0.0f) ? -1.0f : 1.0f;
  a0 = a0*sg; b0 = b0*sg; c0 = c0*sg;

  if (threadIdx.x == 0){
    float* mp = &models[(size_t)t*4];
    mp[0]=a0; mp[1]=b0; mp[2]=c0; mp[3]=d0;
  }
}

// ---------------- Kernel 2: inlier counting (R6/R8-proven body) + fused last-block scan ----------------
// Count body verbatim R6/R8/R10. Arrival WITHOUT __threadfence (R11 regression
// post-mortem: the device-scope fence lowers to a per-block L2 writeback/
// invalidate on gfx950's non-coherent L2s — 1280 of them destroyed L2 reuse,
// FETCH 6.2->31MB, 52us). Ordering is already guaranteed: counts updates and
// the done increment are both device-scope atomics performed at the coherent
// point, and __syncthreads()'s s_waitcnt vmcnt(0) drain (guide m97) retires
// the counts atomics before lane 0 issues the done add. The last block reads
// counts via AGENT-scope atomic loads (bypasses stale local caches, G16).
// No spin-waits; deterministic; state re-zeroed by models_kernel each launch.

__global__ void __launch_bounds__(256) count_scan_kernel(const float* __restrict__ data,
                                                         const float* __restrict__ models,
                                                         int* __restrict__ counts,
                                                         int* __restrict__ done,
                                                         float* __restrict__ out){
  const int g = blockIdx.x % NGRP;       // model group 0..4
  const int c = blockIdx.x / NGRP;       // point chunk 0..7 (4096 pts each)
  const int b = blockIdx.y;              // batch 0..31
  const int tid = (int)threadIdx.x;

  float4 mv[MGRP];
  #pragma unroll
  for (int j=0;j<MGRP;j++)
    mv[j] = ((const float4*)models)[(g*MGRP + j)*BB + b];   // uniform (broadcast)

  const float* dp = data + (size_t)b*NPTS*3 + (size_t)c*4096*3;
  int cnt[MGRP];
  #pragma unroll
  for (int j=0;j<MGRP;j++) cnt[j] = 0;

  #pragma unroll
  for (int i=0;i<4;i++){
    // thread handles 4 consecutive points: base float offset 12*(i*256+tid), 48B-aligned
    const float4* q = (const float4*)(dp + 12*(i*256 + tid));
    float4 f0 = q[0];
    float4 f1 = q[1];
    float4 f2 = q[2];
    float px[4], py[4], pz[4];
    px[0]=f0.x; py[0]=f0.y; pz[0]=f0.z;
    px[1]=f0.w; py[1]=f1.x; pz[1]=f1.y;
    px[2]=f1.z; py[2]=f1.w; pz[2]=f2.x;
    px[3]=f2.y; py[3]=f2.z; pz[3]=f2.w;
    #pragma unroll
    for (int j=0;j<MGRP;j++){
      #pragma unroll
      for (int k=0;k<4;k++){
        // numpy einsum order, separate rounding (no FMA): ((a*x + b*y) + c*z) + d
        float sv = __fmul_rn(mv[j].x, px[k]);
        sv = __fadd_rn(sv, __fmul_rn(mv[j].y, py[k]));
        sv = __fadd_rn(sv, __fmul_rn(mv[j].z, pz[k]));
        sv = __fadd_rn(sv, mv[j].w);
        cnt[j] += (int)__popcll(__ballot(fabsf(sv) < 0.05f));
      }
    }
  }
  // wave-uniform counts (ballot); one atomicAdd per wave per model
  if ((tid & 63) == 0){
    #pragma unroll
    for (int j=0;j<MGRP;j++)
      atomicAdd(&counts[(g*MGRP + j)*BB + b], cnt[j]);
  }

  // ---- arrival: last block to finish runs the scan (no fence; see header) ----
  __shared__ int s_last;
  __syncthreads();                       // drains this block's count atomics (vmcnt(0) before s_barrier)
  if (tid == 0){
    int old = atomicAdd(done, 1);        // device-scope atomic at coherent point
    s_last = (old == CBLOCKS-1) ? 1 : 0;
  }
  __syncthreads();
  if (s_last == 0) return;

  // ---- scan + output (R4-proven logic; 256 threads; coherent count reads) ----
  __shared__ int   icarr[NIT*BB];
  __shared__ int   pmarr[NIT*BB];
  __shared__ float karr[NIT*BB];
  __shared__ int   sdone[NIT];
  __shared__ int   sistop;
  for (int t2 = tid; t2 < NIT*BB; t2 += 256)
    icarr[t2] = __hip_atomic_load(&counts[t2], __ATOMIC_RELAXED, __HIP_MEMORY_SCOPE_AGENT);
  __syncthreads();
  if (tid < BB){
    int pm = 0;
    for (int it=0; it<NIT; it++){
      int ic = icarr[it*BB + tid];
      pm = (ic > pm) ? ic : pm;
      pmarr[it*BB + tid] = pm;
    }
  }
  __syncthreads();
  for (int t2 = tid; t2 < NIT*BB; t2 += 256){
    float p = (float)pmarr[t2] / 32768.0f;
    float p3 = (p*p)*p;
    float prob = fminf(1.0f - p3, 0.99f);
    karr[t2] = -0.35667494393873245f / (logf(prob) + 1e-10f);
  }
  __syncthreads();
  if (tid < NIT){
    float kmax = karr[tid*BB];
    for (int bb=1;bb<BB;bb++) kmax = fmaxf(kmax, karr[tid*BB + bb]);
    int reason = (int)kmax;            // astype(int32): trunc toward zero
    if (reason > 100) reason = 100;
    sdone[tid] = ((tid+1) >= reason) ? 1 : 0;
  }
  __syncthreads();
  if (tid == 0){
    int is = NIT-1;                    // guaranteed hit at it<=34 (reason<=35)
    for (int it=0; it<NIT; it++){ if (sdone[it]){ is = it; break; } }
    sistop = is;
  }
  __syncthreads();
  if (tid < BB){
    const int istop = sistop;
    int best = 0, bit = -1;
    for (int it=0; it<=istop; it++){
      int ic = icarr[it*BB + tid];
      if (ic > best){ best = ic; bit = it; }
    }
    float4 m = make_float4(0.0f,0.0f,0.0f,0.0f);
    if (bit >= 0) m = ((const float4*)models)[bit*BB + tid];
    ((float4*)out)[tid] = m;
  }
}

// ---------------- launch ----------------

extern "C" void kernel_launch(void* const* d_in, const int* in_sizes, int n_in,
                              void* d_out, int out_size, void* d_ws, size_t ws_size,
                              hipStream_t stream){
  const float* data = (const float*)d_in[0];
  const int*   idx  = (const int*)d_in[1];
  float* out = (float*)d_out;
  float* models = (float*)d_ws;                                        // NIT*32*4 floats
  int*   counts = (int*)((char*)d_ws + (size_t)NIT*BB*4*sizeof(float)); // NIT*32 ints
  int*   done   = counts + NIT*BB;                                     // 1 int arrival counter

  models_kernel<<<NIT*BB, 64, 0, stream>>>(data, idx, models, counts, done);
  count_scan_kernel<<<dim3(NGRP*8, BB), 256, 0, stream>>>(data, models, counts, done, out);
}

// Round 13
// 99.977 us; speedup vs baseline: 1.2170x; 1.0405x over previous
//
#include <hip/hip_runtime.h>
#include <math.h>

// Match x86 reference LAPACK (no FMA contraction anywhere in the emulation).
#pragma clang fp contract(off)

#define NIT 35      // provable: prob=min(...,0.99)<=0.99 => k<=35.49 => reason<=35 => no update past it=34
#define BB  32
#define NPTS 32768
#define MGRP 7      // models per count-block
#define NGRP 5      // NIT = MGRP * NGRP

// ---------------- LAPACK helpers (fp32, faithful) ----------------

__device__ __forceinline__ float slapy2f(float x, float y){
  float xa = fabsf(x), ya = fabsf(y);
  float w = fmaxf(xa, ya), z = fminf(xa, ya);
  if (z == 0.0f) return w;
  float q = z / w;
  return w * sqrtf(1.0f + q*q);
}

// LAPACK >= 3.10 slartg (modern OpenBLAS as shipped with numpy/scipy).
__device__ __forceinline__ void slartgf(float f, float g, float* cs, float* sn, float* r){
  if (g == 0.0f){ *cs = 1.0f; *sn = 0.0f; *r = f; return; }
  if (f == 0.0f){ *cs = 0.0f; *sn = copysignf(1.0f, g); *r = fabsf(g); return; }
  float f1 = fabsf(f);
  float d  = sqrtf(f*f + g*g);
  *cs = f1 / d;
  *r  = copysignf(d, f);
  *sn = g / (*r);
}

__device__ void slaev2f(float a, float b, float c,
                        float* rt1, float* rt2, float* cs1, float* sn1){
  float sm  = a + c;
  float df  = a - c;
  float adf = fabsf(df);
  float tb  = b + b;
  float ab  = fabsf(tb);
  float acmx, acmn;
  if (fabsf(a) > fabsf(c)){ acmx = a; acmn = c; } else { acmx = c; acmn = a; }
  float rt;
  if (adf > ab){ float q = ab/adf; rt = adf*sqrtf(1.0f + q*q); }
  else if (adf < ab){ float q = adf/ab; rt = ab*sqrtf(1.0f + q*q); }
  else rt = ab*sqrtf(2.0f);
  int sgn1;
  if (sm < 0.0f){
    *rt1 = 0.5f*(sm - rt); sgn1 = -1;
    *rt2 = (acmx / *rt1)*acmn - (b / *rt1)*b;
  } else if (sm > 0.0f){
    *rt1 = 0.5f*(sm + rt); sgn1 = 1;
    *rt2 = (acmx / *rt1)*acmn - (b / *rt1)*b;
  } else {
    *rt1 = 0.5f*rt; *rt2 = -0.5f*rt; sgn1 = 1;
  }
  float cs; int sgn2;
  if (df >= 0.0f){ cs = df + rt; sgn2 = 1; } else { cs = df - rt; sgn2 = -1; }
  float acs = fabsf(cs);
  float cs1v, sn1v;
  if (acs > ab){
    float ct = -tb/cs;
    sn1v = 1.0f/sqrtf(1.0f + ct*ct);
    cs1v = ct*sn1v;
  } else {
    if (ab == 0.0f){ cs1v = 1.0f; sn1v = 0.0f; }
    else {
      float tn = -cs/tb;
      cs1v = 1.0f/sqrtf(1.0f + tn*tn);
      sn1v = tn*cs1v;
    }
  }
  if (sgn1 == sgn2){ float t = cs1v; cs1v = -sn1v; sn1v = t; }
  *cs1 = cs1v; *sn1 = sn1v;
}

// ---- register-resident dynamic access (R2-proven text) — cold paths only ----
#define RD_D(i)   ((i)==1?d1:(i)==2?d2:(i)==3?d3:d4)
#define WR_D(i,v) do{ float _v=(v); int _ix=(i); if(_ix==1)d1=_v; else if(_ix==2)d2=_v; else if(_ix==3)d3=_v; else d4=_v; }while(0)
#define RD_E(i)   ((i)==1?e1:(i)==2?e2:(i)==3?e3:e4)
#define WR_E(i,v) do{ float _v=(v); int _ix=(i); if(_ix==1)e1=_v; else if(_ix==2)e2=_v; else if(_ix==3)e3=_v; else e4=_v; }while(0)
#define RD_W(i)   ((i)==1?w1:(i)==2?w2:(i)==3?w3:(i)==4?w4:(i)==5?w5:(i)==6?w6:w7)
#define WR_W(i,v) do{ float _v=(v); int _ix=(i); if(_ix==1)w1=_v; else if(_ix==2)w2=_v; else if(_ix==3)w3=_v; else if(_ix==4)w4=_v; else if(_ix==5)w5=_v; else if(_ix==6)w6=_v; else w7=_v; }while(0)
#define RD_Z(i,j) ((j)==1? z##i##1 : (j)==2? z##i##2 : (j)==3? z##i##3 : z##i##4)
#define WR_Z(i,j,v) do{ float _vv=(v); int _jj=(j); \
  if(_jj==1) z##i##1=_vv; else if(_jj==2) z##i##2=_vv; else if(_jj==3) z##i##3=_vv; else z##i##4=_vv; }while(0)
#define ROTZ_ROW(i,jv,cv,sv) do{ \
  float _t = RD_Z(i,(jv)); float _o = RD_Z(i,(jv)-1); \
  float _nt = (cv)*_t - (sv)*_o; \
  float _no = (sv)*_t + (cv)*_o; \
  WR_Z(i,(jv),_nt); WR_Z(i,(jv)-1,_no); \
}while(0)
#define ROTZ(jv,cv,sv) do{ int _rj=(jv); float _rc=(cv), _rs=(sv); \
  ROTZ_ROW(1,_rj,_rc,_rs); ROTZ_ROW(2,_rj,_rc,_rs); ROTZ_ROW(3,_rj,_rc,_rs); ROTZ_ROW(4,_rj,_rc,_rs); }while(0)

// ---------------- Kernel 1: one (it,b) problem per WAVE (verbatim R10-proven) ----------------

__global__ void __launch_bounds__(64) models_kernel(const float* __restrict__ data,
                                                    const int* __restrict__ idx,
                                                    float* __restrict__ models,
                                                    int* __restrict__ counts){
  const int t = blockIdx.x;              // 0..NIT*BB-1; all 64 lanes compute redundantly
  if (threadIdx.x == 0) counts[t] = 0;   // count_kernel is a later dispatch; stream order safe
  const int it = t >> 5;
  const int b  = t & 31;

  // gather 3 samples, aug rows [x,y,z,1]
  float P[3][4];
  const int* ip = &idx[(it*BB + b)*3];
  #pragma unroll
  for (int s=0;s<3;s++){
    int n = ip[s];
    const float* pp = &data[((long)b*NPTS + n)*3];
    P[s][0]=pp[0]; P[s][1]=pp[1]; P[s][2]=pp[2]; P[s][3]=1.0f;
  }
  // A = aug^T aug (sum over s in order 0,1,2; separate rounding)
  float A[5][5];
  #pragma unroll
  for (int i=0;i<4;i++)
    #pragma unroll
    for (int j=0;j<4;j++){
      float acc = P[0][i]*P[0][j];
      acc = acc + P[1][i]*P[1][j];
      acc = acc + P[2][i]*P[2][j];
      A[i+1][j+1] = acc;
    }

  // ssytd2 (UPLO='L', n=4): reference-BLAS op ordering
  float eE[5], tauv[4];
  #pragma unroll
  for (int i=1;i<=3;i++){
    float alpha = A[i+1][i];
    float ssq = 0.0f;
    #pragma unroll
    for (int k=i+2;k<=4;k++) ssq = ssq + A[k][i]*A[k][i];
    float xnorm = sqrtf(ssq);
    float taui;
    if (xnorm == 0.0f){
      taui = 0.0f;
    } else {
      float beta = -copysignf(slapy2f(alpha, xnorm), alpha);
      taui = (beta - alpha)/beta;
      float sc = 1.0f/(alpha - beta);
      #pragma unroll
      for (int k=i+2;k<=4;k++) A[k][i] = A[k][i]*sc;
      alpha = beta;
    }
    eE[i] = alpha;
    if (taui != 0.0f){
      A[i+1][i] = 1.0f;
      float w[5];
      #pragma unroll
      for (int r=i+1;r<=4;r++) w[r] = 0.0f;
      // ssymv('L'): w = taui * Asub * v
      #pragma unroll
      for (int j=i+1;j<=4;j++){
        float temp1 = taui*A[j][i];
        float temp2 = 0.0f;
        w[j] = w[j] + temp1*A[j][j];
        #pragma unroll
        for (int r=j+1;r<=4;r++){
          w[r] = w[r] + temp1*A[r][j];
          temp2 = temp2 + A[r][j]*A[r][i];
        }
        w[j] = w[j] + taui*temp2;
      }
      float dot = 0.0f;
      #pragma unroll
      for (int r=i+1;r<=4;r++) dot = dot + w[r]*A[r][i];
      float alpha2 = (-0.5f*taui)*dot;
      #pragma unroll
      for (int r=i+1;r<=4;r++) w[r] = w[r] + alpha2*A[r][i];
      // ssyr2('L', alpha=-1)
      #pragma unroll
      for (int j=i+1;j<=4;j++){
        float xj = A[j][i], yj = w[j];
        if (xj != 0.0f || yj != 0.0f){
          float temp1 = -yj;
          float temp2 = -xj;
          #pragma unroll
          for (int r=j;r<=4;r++){
            float acc = A[r][j] + A[r][i]*temp1;
            acc = acc + w[r]*temp2;
            A[r][j] = acc;
          }
        }
      }
    }
    tauv[i] = taui;
  }

  // ---------------- ssteqr('I', n=4), all state in registers ----------------
  float d1=A[1][1], d2=A[2][2], d3=A[3][3], d4=A[4][4];
  float e1=eE[1], e2=eE[2], e3=eE[3], e4=0.0f;
  float w1=0,w2=0,w3=0,w4=0,w5=0,w6=0,w7=0;
  float z11=1,z12=0,z13=0,z14=0;
  float z21=0,z22=1,z23=0,z24=0;
  float z31=0,z32=0,z33=1,z34=0;
  float z41=0,z42=0,z43=0,z44=1;
  (void)e4; (void)w7;

  {
    const float eps    = 5.9604645e-08f;
    const float eps2   = eps*eps;
    const float safmin = 1.17549435e-38f;
    const int nmaxit = 4*30;
    int jtot = 0;

    int l1 = 1;
    while (l1 <= 4){
      if (l1 > 1) WR_E(l1-1, 0.0f);
      // ---- outer m-scan, statically unrolled on l1 (R8-proven) ----
      int m = 4;
      do {
        if (l1 == 1){
          float tst = fabsf(e1);
          if (tst == 0.0f){ m = 1; break; }
          if (tst <= (sqrtf(fabsf(d1)) * sqrtf(fabsf(d2))) * eps){ e1 = 0.0f; m = 1; break; }
        }
        if (l1 <= 2){
          float tst = fabsf(e2);
          if (tst == 0.0f){ m = 2; break; }
          if (tst <= (sqrtf(fabsf(d2)) * sqrtf(fabsf(d3))) * eps){ e2 = 0.0f; m = 2; break; }
        }
        if (l1 <= 3){
          float tst = fabsf(e3);
          if (tst == 0.0f){ m = 3; break; }
          if (tst <= (sqrtf(fabsf(d3)) * sqrtf(fabsf(d4))) * eps){ e3 = 0.0f; m = 3; break; }
        }
      } while(0);
      int l = l1, lsv = l, lend = m, lendsv = lend;
      l1 = m + 1;
      if (lend == l) continue;

      // ---- anorm + direction swap, statically specialized (R10-proven) ----
      {
        float anorm; bool sw;
        if (l == 1){
          if (lend == 2){
            anorm = fmaxf(fmaxf(0.0f, fabsf(d1)), fabsf(d2));
            anorm = fmaxf(anorm, fabsf(e1));
            sw = fabsf(d2) < fabsf(d1);
          } else if (lend == 3){
            anorm = fmaxf(fmaxf(fmaxf(0.0f, fabsf(d1)), fabsf(d2)), fabsf(d3));
            anorm = fmaxf(fmaxf(anorm, fabsf(e1)), fabsf(e2));
            sw = fabsf(d3) < fabsf(d1);
          } else {
            anorm = fmaxf(fmaxf(fmaxf(fmaxf(0.0f, fabsf(d1)), fabsf(d2)), fabsf(d3)), fabsf(d4));
            anorm = fmaxf(fmaxf(fmaxf(anorm, fabsf(e1)), fabsf(e2)), fabsf(e3));
            sw = fabsf(d4) < fabsf(d1);
          }
        } else if (l == 2){
          if (lend == 3){
            anorm = fmaxf(fmaxf(0.0f, fabsf(d2)), fabsf(d3));
            anorm = fmaxf(anorm, fabsf(e2));
            sw = fabsf(d3) < fabsf(d2);
          } else {
            anorm = fmaxf(fmaxf(fmaxf(0.0f, fabsf(d2)), fabsf(d3)), fabsf(d4));
            anorm = fmaxf(fmaxf(anorm, fabsf(e2)), fabsf(e3));
            sw = fabsf(d4) < fabsf(d2);
          }
        } else { // l==3, lend==4
          anorm = fmaxf(fmaxf(0.0f, fabsf(d3)), fabsf(d4));
          anorm = fmaxf(anorm, fabsf(e3));
          sw = fabsf(d4) < fabsf(d3);
        }
        if (anorm == 0.0f) continue;
        if (sw){ lend = lsv; l = lendsv; }
      }

      if (lend > l){
        // ---------------- QL iteration ----------------
        for(;;){
          // ---- inner deflation scan, statically unrolled (R8-proven) ----
          int m2 = lend;
          if (l != lend){
            do {
              if (l <= 1){                    // mm=1 (lend>=2 since lend>l)
                float tst = e1*e1;
                if (tst <= (eps2*fabsf(d1))*fabsf(d2) + safmin){ m2 = 1; break; }
              }
              if (l <= 2 && lend >= 3){       // mm=2
                float tst = e2*e2;
                if (tst <= (eps2*fabsf(d2))*fabsf(d3) + safmin){ m2 = 2; break; }
              }
              if (l <= 3 && lend >= 4){       // mm=3
                float tst = e3*e3;
                if (tst <= (eps2*fabsf(d3))*fabsf(d4) + safmin){ m2 = 3; break; }
              }
            } while(0);
          }
          if (m2 < lend) WR_E(m2, 0.0f);
          float p = RD_D(l);
          if (m2 == l){
            WR_D(l, p); l = l + 1;
            if (l <= lend) continue;
            break;
          }
          if (m2 == l+1){
            float rt1, rt2, c1, s1;
            if (l == 1){
              slaev2f(d1, e1, d2, &rt1, &rt2, &c1, &s1);
              w1 = c1; w4 = s1;
              ROTZ(2, c1, s1);
              d1 = rt1; d2 = rt2; e1 = 0.0f;
            } else if (l == 2){
              slaev2f(d2, e2, d3, &rt1, &rt2, &c1, &s1);
              w2 = c1; w5 = s1;
              ROTZ(3, c1, s1);
              d2 = rt1; d3 = rt2; e2 = 0.0f;
            } else {
              slaev2f(d3, e3, d4, &rt1, &rt2, &c1, &s1);
              w3 = c1; w6 = s1;
              ROTZ(4, c1, s1);
              d3 = rt1; d4 = rt2; e3 = 0.0f;
            }
            l = l + 2;
            if (l <= lend) continue;
            break;
          }
          if (jtot == nmaxit) break;
          jtot++;
          {
            float g, r, s = 1.0f, c = 1.0f;
            if (l == 1 && m2 == 3){
              g = (d2 - p) / (2.0f*e1);
              r = slapy2f(g, 1.0f);
              g = d3 - p + (e1 / (g + copysignf(r, g)));
              p = 0.0f;
              { // i=2 (first: no e-write)
                float f = s*e2, bq = c*e2;
                slartgf(g, f, &c, &s, &r);
                g = d3 - p;
                r = (d2 - g)*s + (2.0f*c)*bq;
                p = s*r;
                d3 = g + p;
                g = c*r - bq;
                w2 = c; w5 = -s;
              }
              { // i=1
                float f = s*e1, bq = c*e1;
                slartgf(g, f, &c, &s, &r);
                e2 = r;
                g = d2 - p;
                r = (d1 - g)*s + (2.0f*c)*bq;
                p = s*r;
                d2 = g + p;
                g = c*r - bq;
                w1 = c; w4 = -s;
              }
              if (w2 != 1.0f || w5 != 0.0f) ROTZ(3, w2, w5);
              if (w1 != 1.0f || w4 != 0.0f) ROTZ(2, w1, w4);
              d1 = d1 - p;
              e1 = g;
            } else if (l == 1 && m2 == 4){
              g = (d2 - p) / (2.0f*e1);
              r = slapy2f(g, 1.0f);
              g = d4 - p + (e1 / (g + copysignf(r, g)));
              p = 0.0f;
              { // i=3 (first)
                float f = s*e3, bq = c*e3;
                slartgf(g, f, &c, &s, &r);
                g = d4 - p;
                r = (d3 - g)*s + (2.0f*c)*bq;
                p = s*r;
                d4 = g + p;
                g = c*r - bq;
                w3 = c; w6 = -s;
              }
              { // i=2
                float f = s*e2, bq = c*e2;
                slartgf(g, f, &c, &s, &r);
                e3 = r;
                g = d3 - p;
                r = (d2 - g)*s + (2.0f*c)*bq;
                p = s*r;
                d3 = g + p;
                g = c*r - bq;
                w2 = c; w5 = -s;
              }
              { // i=1
                float f = s*e1, bq = c*e1;
                slartgf(g, f, &c, &s, &r);
                e2 = r;
                g = d2 - p;
                r = (d1 - g)*s + (2.0f*c)*bq;
                p = s*r;
                d2 = g + p;
                g = c*r - bq;
                w1 = c; w4 = -s;
              }
              if (w3 != 1.0f || w6 != 0.0f) ROTZ(4, w3, w6);
              if (w2 != 1.0f || w5 != 0.0f) ROTZ(3, w2, w5);
              if (w1 != 1.0f || w4 != 0.0f) ROTZ(2, w1, w4);
              d1 = d1 - p;
              e1 = g;
            } else if (l == 2 && m2 == 4){
              g = (d3 - p) / (2.0f*e2);
              r = slapy2f(g, 1.0f);
              g = d4 - p + (e2 / (g + copysignf(r, g)));
              p = 0.0f;
              { // i=3 (first)
                float f = s*e3, bq = c*e3;
                slartgf(g, f, &c, &s, &r);
                g = d4 - p;
                r = (d3 - g)*s + (2.0f*c)*bq;
                p = s*r;
                d4 = g + p;
                g = c*r - bq;
                w3 = c; w6 = -s;
              }
              { // i=2
                float f = s*e2, bq = c*e2;
                slartgf(g, f, &c, &s, &r);
                e3 = r;
                g = d3 - p;
                r = (d2 - g)*s + (2.0f*c)*bq;
                p = s*r;
                d3 = g + p;
                g = c*r - bq;
                w2 = c; w5 = -s;
              }
              if (w3 != 1.0f || w6 != 0.0f) ROTZ(4, w3, w6);
              if (w2 != 1.0f || w5 != 0.0f) ROTZ(3, w2, w5);
              d2 = d2 - p;
              e2 = g;
            } else {
              // defensive fallback: original dynamic text
              g = (RD_D(l+1) - p) / (2.0f*RD_E(l));
              r = slapy2f(g, 1.0f);
              g = RD_D(m2) - p + (RD_E(l) / (g + copysignf(r, g)));
              s = 1.0f; c = 1.0f;
              p = 0.0f;
              for (int i = m2-1; i >= l; i--){
                float f  = s*RD_E(i);
                float bq = c*RD_E(i);
                slartgf(g, f, &c, &s, &r);
                if (i != m2-1) WR_E(i+1, r);
                g = RD_D(i+1) - p;
                r = (RD_D(i) - g)*s + (2.0f*c)*bq;
                p = s*r;
                WR_D(i+1, g + p);
                g = c*r - bq;
                WR_W(i, c);
                WR_W(3+i, -s);
              }
              int mmn = m2 - l + 1;    // slasr('R','V','B')
              for (int j = mmn-1; j >= 1; j--){
                float ct = RD_W(l+j-1), sx = RD_W(3+l+j-1);
                if (ct != 1.0f || sx != 0.0f) ROTZ(l+j, ct, sx);
              }
              WR_D(l, RD_D(l) - p);
              WR_E(l, g);
            }
          }
        }
      } else {
        // ---------------- QR iteration ----------------
        for(;;){
          // ---- inner deflation scan, statically unrolled (R8-proven) ----
          int m2 = lend;
          if (l != lend){
            do {
              if (l >= 4){                    // mm=4 (lend<=3 since lend<l)
                float tst = e3*e3;
                if (tst <= (eps2*fabsf(d4))*fabsf(d3) + safmin){ m2 = 4; break; }
              }
              if (l >= 3 && lend <= 2){       // mm=3
                float tst = e2*e2;
                if (tst <= (eps2*fabsf(d3))*fabsf(d2) + safmin){ m2 = 3; break; }
              }
              if (l >= 2 && lend <= 1){       // mm=2
                float tst = e1*e1;
                if (tst <= (eps2*fabsf(d2))*fabsf(d1) + safmin){ m2 = 2; break; }
              }
            } while(0);
          }
          if (m2 > lend) WR_E(m2-1, 0.0f);
          float p = RD_D(l);
          if (m2 == l){
            WR_D(l, p); l = l - 1;
            if (l >= lend) continue;
            break;
          }
          if (m2 == l-1){
            float rt1, rt2, c1, s1;
            if (l == 2){
              slaev2f(d1, e1, d2, &rt1, &rt2, &c1, &s1);
              w1 = c1; w4 = s1;
              ROTZ(2, c1, s1);
              d1 = rt1; d2 = rt2; e1 = 0.0f;
            } else if (l == 3){
              slaev2f(d2, e2, d3, &rt1, &rt2, &c1, &s1);
              w2 = c1; w5 = s1;
              ROTZ(3, c1, s1);
              d2 = rt1; d3 = rt2; e2 = 0.0f;
            } else {
              slaev2f(d3, e3, d4, &rt1, &rt2, &c1, &s1);
              w3 = c1; w6 = s1;
              ROTZ(4, c1, s1);
              d3 = rt1; d4 = rt2; e3 = 0.0f;
            }
            l = l - 2;
            if (l >= lend) continue;
            break;
          }
          if (jtot == nmaxit) break;
          jtot++;
          {
            float g, r, s = 1.0f, c = 1.0f;
            if (l == 3 && m2 == 1){
              g = (d2 - p) / (2.0f*e2);
              r = slapy2f(g, 1.0f);
              g = d1 - p + (e2 / (g + copysignf(r, g)));
              p = 0.0f;
              { // i=1 (first: no e-write)
                float f = s*e1, bq = c*e1;
                slartgf(g, f, &c, &s, &r);
                g = d1 - p;
                r = (d2 - g)*s + (2.0f*c)*bq;
                p = s*r;
                d1 = g + p;
                g = c*r - bq;
                w1 = c; w4 = s;
              }
              { // i=2
                float f = s*e2, bq = c*e2;
                slartgf(g, f, &c, &s, &r);
                e1 = r;
                g = d2 - p;
                r = (d3 - g)*s + (2.0f*c)*bq;
                p = s*r;
                d2 = g + p;
                g = c*r - bq;
                w2 = c; w5 = s;
              }
              if (w1 != 1.0f || w4 != 0.0f) ROTZ(2, w1, w4);
              if (w2 != 1.0f || w5 != 0.0f) ROTZ(3, w2, w5);
              d3 = d3 - p;
              e2 = g;
            } else if (l == 4 && m2 == 1){
              g = (d3 - p) / (2.0f*e3);
              r = slapy2f(g, 1.0f);
              g = d1 - p + (e3 / (g + copysignf(r, g)));
              p = 0.0f;
              { // i=1 (first)
                float f = s*e1, bq = c*e1;
                slartgf(g, f, &c, &s, &r);
                g = d1 - p;
                r = (d2 - g)*s + (2.0f*c)*bq;
                p = s*r;
                d1 = g + p;
                g = c*r - bq;
                w1 = c; w4 = s;
              }
              { // i=2
                float f = s*e2, bq = c*e2;
                slartgf(g, f, &c, &s, &r);
                e1 = r;
                g = d2 - p;
                r = (d3 - g)*s + (2.0f*c)*bq;
                p = s*r;
                d2 = g + p;
                g = c*r - bq;
                w2 = c; w5 = s;
              }
              { // i=3
                float f = s*e3, bq = c*e3;
                slartgf(g, f, &c, &s, &r);
                e2 = r;
                g = d3 - p;
                r = (d4 - g)*s + (2.0f*c)*bq;
                p = s*r;
                d3 = g + p;
                g = c*r - bq;
                w3 = c; w6 = s;
              }
              if (w1 != 1.0f || w4 != 0.0f) ROTZ(2, w1, w4);
              if (w2 != 1.0f || w5 != 0.0f) ROTZ(3, w2, w5);
              if (w3 != 1.0f || w6 != 0.0f) ROTZ(4, w3, w6);
              d4 = d4 - p;
              e3 = g;
            } else if (l == 4 && m2 == 2){
              g = (d3 - p) / (2.0f*e3);
              r = slapy2f(g, 1.0f);
              g = d2 - p + (e3 / (g + copysignf(r, g)));
              p = 0.0f;
              { // i=2 (first)
                float f = s*e2, bq = c*e2;
                slartgf(g, f, &c, &s, &r);
                g = d2 - p;
                r = (d3 - g)*s + (2.0f*c)*bq;
                p = s*r;
                d2 = g + p;
                g = c*r - bq;
                w2 = c; w5 = s;
              }
              { // i=3
                float f = s*e3, bq = c*e3;
                slartgf(g, f, &c, &s, &r);
                e2 = r;
                g = d3 - p;
                r = (d4 - g)*s + (2.0f*c)*bq;
                p = s*r;
                d3 = g + p;
                g = c*r - bq;
                w3 = c; w6 = s;
              }
              if (w2 != 1.0f || w5 != 0.0f) ROTZ(3, w2, w5);
              if (w3 != 1.0f || w6 != 0.0f) ROTZ(4, w3, w6);
              d4 = d4 - p;
              e3 = g;
            } else {
              // defensive fallback: original dynamic text
              g = (RD_D(l-1) - p) / (2.0f*RD_E(l-1));
              r = slapy2f(g, 1.0f);
              g = RD_D(m2) - p + (RD_E(l-1) / (g + copysignf(r, g)));
              s = 1.0f; c = 1.0f;
              p = 0.0f;
              for (int i = m2; i <= l-1; i++){
                float f  = s*RD_E(i);
                float bq = c*RD_E(i);
                slartgf(g, f, &c, &s, &r);
                if (i != m2) WR_E(i-1, r);
                g = RD_D(i) - p;
                r = (RD_D(i+1) - g)*s + (2.0f*c)*bq;
                p = s*r;
                WR_D(i, g + p);
                g = c*r - bq;
                WR_W(i, c);
                WR_W(3+i, s);
              }
              int mmn = l - m2 + 1;    // slasr('R','V','F')
              for (int j = 1; j <= mmn-1; j++){
                float ct = RD_W(m2+j-1), sx = RD_W(3+m2+j-1);
                if (ct != 1.0f || sx != 0.0f) ROTZ(m2+j, ct, sx);
              }
              WR_D(l, RD_D(l) - p);
              WR_E(l-1, g);
            }
          }
        }
      }
      if (jtot >= nmaxit) break;
    }
  }

  // argmin eigenvalue (first minimum — matches ssteqr selection-sort rank-0 pick)
  int kbest = 1;
  float dmin = d1;
  if (d2 < dmin){ dmin = d2; kbest = 2; }
  if (d3 < dmin){ dmin = d3; kbest = 3; }
  if (d4 < dmin){ dmin = d4; kbest = 4; }
  float zc1 = RD_Z(1,kbest);
  float zc2 = RD_Z(2,kbest);
  float zc3 = RD_Z(3,kbest);
  float zc4 = RD_Z(4,kbest);

  // sormtr: apply Q = H1*H2 (H2 first, then H1); H3 has tau=0
  {
    float v2 = A[4][2];
    float sum = zc3 + v2*zc4;
    float tt = tauv[2]*sum;
    zc3 = zc3 - tt;
    zc4 = zc4 - tt*v2;
  }
  {
    float va = A[3][1], vb = A[4][1];
    float sum = zc2 + va*zc3;
    sum = sum + vb*zc4;
    float tt = tauv[1]*sum;
    zc2 = zc2 - tt;
    zc3 = zc3 - tt*va;
    zc4 = zc4 - tt*vb;
  }

  // reference post-process: normalize by ||(a,b,c)||, sign-fix abc only
  float n2 = zc1*zc1;
  n2 = n2 + zc2*zc2;
  n2 = n2 + zc3*zc3;
  float nrm = sqrtf(n2);
  float a0 = zc1/nrm;
  float b0 = zc2/nrm;
  float c0 = zc3/nrm;
  float d0 = zc4/nrm;
  float sg = (b0 < 0.0f) ? -1.0f : 1.0f;
  a0 = a0*sg; b0 = b0*sg; c0 = c0*sg;

  if (threadIdx.x == 0){
    float* mp = &models[(size_t)t*4];
    mp[0]=a0; mp[1]=b0; mp[2]=c0; mp[3]=d0;
  }
}

// ---------------- Kernel 2: inlier counting, model-group blocked (verbatim R6/R8, proven) ----------------

__global__ void __launch_bounds__(256) count_kernel(const float* __restrict__ data,
                                                    const float* __restrict__ models,
                                                    int* __restrict__ counts){
  const int g = blockIdx.x % NGRP;       // model group 0..4
  const int c = blockIdx.x / NGRP;       // point chunk 0..7 (4096 pts each)
  const int b = blockIdx.y;              // batch 0..31
  const int tid = (int)threadIdx.x;

  float4 mv[MGRP];
  #pragma unroll
  for (int j=0;j<MGRP;j++)
    mv[j] = ((const float4*)models)[(g*MGRP + j)*BB + b];   // uniform (broadcast)

  const float* dp = data + (size_t)b*NPTS*3 + (size_t)c*4096*3;
  int cnt[MGRP];
  #pragma unroll
  for (int j=0;j<MGRP;j++) cnt[j] = 0;

  #pragma unroll
  for (int i=0;i<4;i++){
    // thread handles 4 consecutive points: base float offset 12*(i*256+tid), 48B-aligned
    const float4* q = (const float4*)(dp + 12*(i*256 + tid));
    float4 f0 = q[0];
    float4 f1 = q[1];
    float4 f2 = q[2];
    float px[4], py[4], pz[4];
    px[0]=f0.x; py[0]=f0.y; pz[0]=f0.z;
    px[1]=f0.w; py[1]=f1.x; pz[1]=f1.y;
    px[2]=f1.z; py[2]=f1.w; pz[2]=f2.x;
    px[3]=f2.y; py[3]=f2.z; pz[3]=f2.w;
    #pragma unroll
    for (int j=0;j<MGRP;j++){
      #pragma unroll
      for (int k=0;k<4;k++){
        // numpy einsum order, separate rounding (no FMA): ((a*x + b*y) + c*z) + d
        float sv = __fmul_rn(mv[j].x, px[k]);
        sv = __fadd_rn(sv, __fmul_rn(mv[j].y, py[k]));
        sv = __fadd_rn(sv, __fmul_rn(mv[j].z, pz[k]));
        sv = __fadd_rn(sv, mv[j].w);
        cnt[j] += (int)__popcll(__ballot(fabsf(sv) < 0.05f));
      }
    }
  }
  // wave-uniform counts (ballot); one atomicAdd per wave per model
  if ((tid & 63) == 0){
    #pragma unroll
    for (int j=0;j<MGRP;j++)
      atomicAdd(&counts[(g*MGRP + j)*BB + b], cnt[j]);
  }
}

// ---------------- Kernel 3: parallel faithful scan + output (verbatim R4/R8, proven) ----------------

__global__ void __launch_bounds__(64) scan_kernel(const int* __restrict__ counts,
                                                  const float* __restrict__ models,
                                                  float* __restrict__ out){
  __shared__ int   icarr[NIT*BB];
  __shared__ int   pmarr[NIT*BB];
  __shared__ float karr[NIT*BB];
  __shared__ int   sdone[NIT];
  __shared__ int   sistop;
  const int lane = threadIdx.x;
  for (int t = lane; t < NIT*BB; t += 64) icarr[t] = counts[t];
  __syncthreads();
  if (lane < BB){
    int pm = 0;
    for (int it=0; it<NIT; it++){
      int ic = icarr[it*BB + lane];
      pm = (ic > pm) ? ic : pm;
      pmarr[it*BB + lane] = pm;
    }
  }
  __syncthreads();
  for (int t = lane; t < NIT*BB; t += 64){
    float p = (float)pmarr[t] / 32768.0f;
    float p3 = (p*p)*p;
    float prob = fminf(1.0f - p3, 0.99f);
    karr[t] = -0.35667494393873245f / (logf(prob) + 1e-10f);
  }
  __syncthreads();
  if (lane < NIT){
    float kmax = karr[lane*BB];
    for (int b=1;b<BB;b++) kmax = fmaxf(kmax, karr[lane*BB + b]);
    int reason = (int)kmax;            // astype(int32): trunc toward zero
    if (reason > 100) reason = 100;
    sdone[lane] = ((lane+1) >= reason) ? 1 : 0;
  }
  __syncthreads();
  if (lane == 0){
    int is = NIT-1;                    // guaranteed hit at it<=34 (reason<=35)
    for (int it=0; it<NIT; it++){ if (sdone[it]){ is = it; break; } }
    sistop = is;
  }
  __syncthreads();
  if (lane < BB){
    const int istop = sistop;
    int best = 0, bit = -1;
    for (int it=0; it<=istop; it++){
      int ic = icarr[it*BB + lane];
      if (ic > best){ best = ic; bit = it; }
    }
    float4 m = make_float4(0.0f,0.0f,0.0f,0.0f);
    if (bit >= 0) m = ((const float4*)models)[bit*BB + lane];
    ((float4*)out)[lane] = m;
  }
}

// ---------------- launch ----------------

extern "C" void kernel_launch(void* const* d_in, const int* in_sizes, int n_in,
                              void* d_out, int out_size, void* d_ws, size_t ws_size,
                              hipStream_t stream){
  const float* data = (const float*)d_in[0];
  const int*   idx  = (const int*)d_in[1];
  float* out = (float*)d_out;
  float* models = (float*)d_ws;                                        // NIT*32*4 floats
  int*   counts = (int*)((char*)d_ws + (size_t)NIT*BB*4*sizeof(float)); // NIT*32 ints

  models_kernel<<<NIT*BB, 64, 0, stream>>>(data, idx, models, counts);
  count_kernel<<<dim3(NGRP*8, BB), 256, 0, stream>>>(data, models, counts);
  scan_kernel<<<1, 64, 0, stream>>>(counts, models, out);
}